// Round 16
// baseline (493.310 us; speedup 1.0000x reference)
//
#include <hip/hip_runtime.h>

#define BATCH 2
#define T 2048
#define E 1024
#define NH 16
#define HD 64
#define M (BATCH*T)   // 4096
#define K3 (3*E)      // 3072
#define VOCAB 32000

typedef __attribute__((ext_vector_type(8))) short s16x8;
typedef __attribute__((ext_vector_type(4))) short s16x4;
typedef __attribute__((ext_vector_type(4))) float f32x4;
typedef __attribute__((ext_vector_type(16))) float f32x16;

__device__ inline unsigned short f2bf(float f) {
  union { float f; unsigned u; } x; x.f = f;
  unsigned r = x.u + 0x7fffu + ((x.u >> 16) & 1u);   // RNE
  return (unsigned short)(r >> 16);
}

__device__ inline void gload16(const void* g, void* l) {
  __builtin_amdgcn_global_load_lds(
      (const __attribute__((address_space(1))) unsigned int*)g,
      (__attribute__((address_space(3))) unsigned int*)l, 16, 0, 0);
}

// ---- weight transpose+convert body: W[1024][N] f32 -> Wt[N][1024] bf16 ----
__device__ inline void wt_body(const float* __restrict__ W,
    unsigned short* __restrict__ Wt, int N, int n0, int k0, int t,
    float (*tile)[65]) {
  int kl = t >> 2, c = t & 3;
  #pragma unroll
  for (int i = 0; i < 4; i++) {
    float4 v4 = *(const float4*)(W + (size_t)(k0 + kl) * N + n0 + c * 16 + i * 4);
    tile[kl][c * 16 + i * 4 + 0] = v4.x;
    tile[kl][c * 16 + i * 4 + 1] = v4.y;
    tile[kl][c * 16 + i * 4 + 2] = v4.z;
    tile[kl][c * 16 + i * 4 + 3] = v4.w;
  }
  __syncthreads();
  #pragma unroll
  for (int j = 0; j < 2; j++) {
    int idx = t + j * 256;
    int nl = idx >> 3, kq = (idx & 7) * 8;
    s16x8 o;
    #pragma unroll
    for (int i = 0; i < 8; i++) o[i] = (short)f2bf(tile[kq + i][nl]);
    *(s16x8*)(Wt + (size_t)(n0 + nl) * 1024 + k0 + kq) = o;
  }
}

// ---------------- k_pre: embed + wt(qkv_w) + wt(proj_w) fused ----------------
__global__ __launch_bounds__(256) void k_pre(const int* __restrict__ x,
    const float* __restrict__ tok, const float* __restrict__ pos,
    unsigned short* __restrict__ hb,
    const float* __restrict__ qkvw, unsigned short* __restrict__ qkvwt,
    const float* __restrict__ projw, unsigned short* __restrict__ projwt) {
  __shared__ __align__(16) float tile[64][65];
  int gid = blockIdx.x, t = threadIdx.x;
  if (gid < 4096) {
    int row = gid;
    int tt = row & (T - 1);
    int tokid = x[row];
    float4 a = ((const float4*)(tok + (size_t)tokid * E))[t];
    float4 p = ((const float4*)(pos + (size_t)tt * E))[t];
    s16x4 o;
    o[0] = (short)f2bf(a.x + p.x); o[1] = (short)f2bf(a.y + p.y);
    o[2] = (short)f2bf(a.z + p.z); o[3] = (short)f2bf(a.w + p.w);
    *(s16x4*)(hb + (size_t)row * E + t * 4) = o;
    return;
  }
  if (gid < 4864) {
    int idx = gid - 4096;
    wt_body(qkvw, qkvwt, K3, (idx % 48) * 64, (idx / 48) * 64, t, tile);
    return;
  }
  int idx = gid - 4864;
  wt_body(projw, projwt, E, (idx % 16) * 64, (idx / 16) * 64, t, tile);
}

// ---------------- bf16 MFMA GEMM 128x128 (m97 structure) ----------------
// MODE 0: fp32 C + bias.  MODE 2: bf16 C + bias.  (used for proj + fallback)
template<int MODE>
__global__ __launch_bounds__(256) void k_bgemm(
    const unsigned short* __restrict__ A, const unsigned short* __restrict__ Bt,
    const float* __restrict__ bias, float* __restrict__ C, int N,
    unsigned short* __restrict__ Cb) {
  __shared__ char lds[16384];
  char* As = lds;
  char* Bs = lds + 8192;
  int tid = threadIdx.x;
  int lane = tid & 63;
  int wv = tid >> 6;
  int wm = wv >> 1, wn = wv & 1;
  int n0 = blockIdx.x * 128, m0 = blockIdx.y * 128;
  int fr = lane & 15, fq = lane >> 4;

  f32x4 acc[4][4];
  #pragma unroll
  for (int i = 0; i < 4; i++)
    #pragma unroll
    for (int j = 0; j < 4; j++) acc[i][j] = (f32x4){0.f, 0.f, 0.f, 0.f};

  int p0 = tid * 16, p1 = tid * 16 + 4096;
  int r0 = p0 >> 6, c0 = p0 & 63;
  int r1 = p1 >> 6, c1 = p1 & 63;
  int cs0 = c0 ^ (((r0 >> 1) & 3) << 4);
  int cs1 = c1 ^ (((r1 >> 1) & 3) << 4);
  const char* ga0 = (const char*)(A + (size_t)(m0 + r0) * 1024) + cs0;
  const char* ga1 = (const char*)(A + (size_t)(m0 + r1) * 1024) + cs1;
  const char* gb0 = (const char*)(Bt + (size_t)(n0 + r0) * 1024) + cs0;
  const char* gb1 = (const char*)(Bt + (size_t)(n0 + r1) * 1024) + cs1;

  int aoff[4], boff[4];
  #pragma unroll
  for (int i = 0; i < 4; i++) {
    int ra = wm * 64 + i * 16 + fr;
    aoff[i] = ra * 64 + ((fq * 16) ^ (((ra >> 1) & 3) << 4));
    int rb = wn * 64 + i * 16 + fr;
    boff[i] = rb * 64 + ((fq * 16) ^ (((rb >> 1) & 3) << 4));
  }

  for (int kb = 0; kb < 2048; kb += 64) {
    gload16(ga0 + kb, As + p0);
    gload16(ga1 + kb, As + p1);
    gload16(gb0 + kb, Bs + p0);
    gload16(gb1 + kb, Bs + p1);
    __syncthreads();
    s16x8 af[4], bfr[4];
    #pragma unroll
    for (int i = 0; i < 4; i++) af[i] = *(const s16x8*)(As + aoff[i]);
    #pragma unroll
    for (int i = 0; i < 4; i++) bfr[i] = *(const s16x8*)(Bs + boff[i]);
    #pragma unroll
    for (int mi = 0; mi < 4; mi++)
      #pragma unroll
      for (int ni = 0; ni < 4; ni++)
        acc[mi][ni] = __builtin_amdgcn_mfma_f32_16x16x32_bf16(
            af[mi], bfr[ni], acc[mi][ni], 0, 0, 0);
    __syncthreads();
  }

  #pragma unroll
  for (int mi = 0; mi < 4; mi++) {
    #pragma unroll
    for (int ni = 0; ni < 4; ni++) {
      #pragma unroll
      for (int j = 0; j < 4; j++) {
        int m = m0 + wm * 64 + mi * 16 + fq * 4 + j;
        int n = n0 + wn * 64 + ni * 16 + fr;
        float val = acc[mi][ni][j] + bias[n];
        if (MODE == 0) C[(size_t)m * N + n] = val;
        else           Cb[(size_t)m * 1024 + n] = f2bf(val);
      }
    }
  }
}

// ---------------- qkv GEMM: R4-256² structure + scatter epilogue ----------------
__global__ __launch_bounds__(512, 2) void k_qkv(
    const unsigned short* __restrict__ A, const unsigned short* __restrict__ Bt,
    const float* __restrict__ bias,
    unsigned short* __restrict__ qo, unsigned short* __restrict__ ko,
    unsigned short* __restrict__ vo) {
  __shared__ __align__(16) char lds[131072];
  int tid = threadIdx.x, lane = tid & 63, wv = tid >> 6;
  int WM = wv >> 2, WN = wv & 3;
  int fr = lane & 15, fq = lane >> 4;

  int bid = blockIdx.x;                 // 192 blocks
  int wg = (bid & 7) * 24 + (bid >> 3); // bijective (192 % 8 == 0)
  int m0 = (wg % 16) * 256;
  int n0 = (wg / 16) * 256;

  const char* gA[4]; const char* gB[4]; int lo[4];
  #pragma unroll
  for (int j = 0; j < 4; j++) {
    int i = tid + j * 512;
    int r = i >> 3, c = i & 7;
    int cc = c ^ (r & 7);
    gA[j] = (const char*)A + ((size_t)(m0 + r) * 1024 + cc * 8) * 2;
    gB[j] = (const char*)Bt + ((size_t)(n0 + r) * 1024 + cc * 8) * 2;
    lo[j] = i * 16;
  }

  f32x4 acc[8][4];
  #pragma unroll
  for (int i = 0; i < 8; i++)
    #pragma unroll
    for (int j = 0; j < 4; j++) acc[i][j] = (f32x4){0.f, 0.f, 0.f, 0.f};

  #pragma unroll
  for (int j = 0; j < 4; j++) {
    gload16(gA[j], lds + lo[j]);
    gload16(gB[j], lds + 65536 + lo[j]);
  }
  __syncthreads();

  for (int t = 0; t < 16; t++) {
    int cur = t & 1;
    if (t + 1 < 16) {
      int kb = (t + 1) * 128;
      int nxt = cur ^ 1;
      #pragma unroll
      for (int j = 0; j < 4; j++) {
        gload16(gA[j] + kb, lds + nxt * 32768 + lo[j]);
        gload16(gB[j] + kb, lds + 65536 + nxt * 32768 + lo[j]);
      }
    }
    const char* As = lds + cur * 32768;
    const char* Bs = lds + 65536 + cur * 32768;
    #pragma unroll
    for (int kh = 0; kh < 2; kh++) {
      s16x8 af[8], bf[4];
      #pragma unroll
      for (int mi = 0; mi < 8; mi++) {
        int r = WM * 128 + mi * 16 + fr;
        af[mi] = *(const s16x8*)(As + r * 128 + (((kh * 4 + fq) ^ (r & 7)) << 4));
      }
      #pragma unroll
      for (int ni = 0; ni < 4; ni++) {
        int r = WN * 64 + ni * 16 + fr;
        bf[ni] = *(const s16x8*)(Bs + r * 128 + (((kh * 4 + fq) ^ (r & 7)) << 4));
      }
      __builtin_amdgcn_s_setprio(1);
      #pragma unroll
      for (int mi = 0; mi < 8; mi++)
        #pragma unroll
        for (int ni = 0; ni < 4; ni++)
          acc[mi][ni] = __builtin_amdgcn_mfma_f32_16x16x32_bf16(
              af[mi], bf[ni], acc[mi][ni], 0, 0, 0);
      __builtin_amdgcn_s_setprio(0);
    }
    __syncthreads();
  }

  #pragma unroll
  for (int mi = 0; mi < 8; mi++) {
    #pragma unroll
    for (int ni = 0; ni < 4; ni++) {
      int n = n0 + WN * 64 + ni * 16 + fr;
      int which = n >> 10;
      int e = n & (E - 1);
      int hh = e >> 6, d = e & 63;
      int mb = m0 + WM * 128 + mi * 16 + fq * 4;
      int b = mb >> 11, tt0 = mb & (T - 1);
      float bv = bias[n];
      if (which == 2) {
        s16x4 pk;
        #pragma unroll
        for (int j = 0; j < 4; j++) pk[j] = (short)f2bf(acc[mi][ni][j] + bv);
        *(s16x4*)(vo + ((size_t)(b * NH + hh) * 64 + d) * T + tt0) = pk;
      } else {
        unsigned short* dst = (which == 0) ? qo : ko;
        #pragma unroll
        for (int j = 0; j < 4; j++)
          dst[((size_t)(b * NH + hh) * T + tt0 + j) * 64 + d] =
              f2bf(acc[mi][ni][j] + bv);
      }
    }
  }
}

// ---------------- fc GEMM: R4 schedule + 32x32x16 MFMA fragments ----------------
// Same staging/sync/swizzle as the x4-reproduced R4 kernel; only the fragment
// shape changes: per K=32 step, 16 MFMA 32x32x16 (8.07 cyc, 2495 TF ceiling)
// replaces 32 MFMA 16x16x32 (4.85 cyc, 2075 TF) — 17% less MFMA-pipe time,
// identical ds_read count. A-frag: m=lane&31, k=(lane>>5)*8+j (analog of the
// verified 16x16 mapping). C/D: col=lane&31, row=(reg&3)+8*(reg>>2)+4*(lane>>5)
// (m74/m101-verified). absmax is the layout checker.
__global__ __launch_bounds__(512, 2) void k_fc(
    const unsigned short* __restrict__ A, const unsigned short* __restrict__ Bt,
    const float* __restrict__ bias, float* __restrict__ C) {
  __shared__ __align__(16) char lds[131072];  // As0|As1 @0,32K ; Bs0|Bs1 @64K,96K
  int tid = threadIdx.x, lane = tid & 63, wv = tid >> 6;
  int WM = wv >> 2, WN = wv & 3;              // 2M x 4N waves, per-wave 128x64
  int l31 = lane & 31, lh = lane >> 5;

  int bid = blockIdx.x;
  int wg = (bid & 7) * 250 + (bid >> 3);
  int m0 = (wg & 15) * 256;
  int n0 = (wg >> 4) * 256;

  const char* gA[4]; const char* gB[4]; int lo[4];
  #pragma unroll
  for (int j = 0; j < 4; j++) {
    int i = tid + j * 512;
    int r = i >> 3, c = i & 7;
    int cc = c ^ (r & 7);
    gA[j] = (const char*)A + ((size_t)(m0 + r) * 1024 + cc * 8) * 2;
    gB[j] = (const char*)Bt + ((size_t)(n0 + r) * 1024 + cc * 8) * 2;
    lo[j] = i * 16;
  }

  f32x16 acc[4][2];
  #pragma unroll
  for (int i = 0; i < 4; i++)
    #pragma unroll
    for (int j = 0; j < 2; j++)
      #pragma unroll
      for (int e = 0; e < 16; e++) acc[i][j][e] = 0.f;

  #pragma unroll
  for (int j = 0; j < 4; j++) {
    gload16(gA[j], lds + lo[j]);
    gload16(gB[j], lds + 65536 + lo[j]);
  }
  __syncthreads();

  for (int t = 0; t < 16; t++) {
    int cur = t & 1;
    if (t + 1 < 16) {
      int kb = (t + 1) * 128;
      int nxt = cur ^ 1;
      #pragma unroll
      for (int j = 0; j < 4; j++) {
        gload16(gA[j] + kb, lds + nxt * 32768 + lo[j]);
        gload16(gB[j] + kb, lds + 65536 + nxt * 32768 + lo[j]);
      }
    }
    const char* As = lds + cur * 32768;
    const char* Bs = lds + 65536 + cur * 32768;
    #pragma unroll
    for (int kh = 0; kh < 2; kh++) {
      s16x8 af[4][2], bf[2][2];
      #pragma unroll
      for (int mb = 0; mb < 4; mb++) {
        int r = WM * 128 + mb * 32 + l31;
        #pragma unroll
        for (int ks = 0; ks < 2; ks++) {
          int ch = kh * 4 + ks * 2 + lh;
          af[mb][ks] = *(const s16x8*)(As + r * 128 + ((ch ^ (r & 7)) << 4));
        }
      }
      #pragma unroll
      for (int nb = 0; nb < 2; nb++) {
        int r = WN * 64 + nb * 32 + l31;
        #pragma unroll
        for (int ks = 0; ks < 2; ks++) {
          int ch = kh * 4 + ks * 2 + lh;
          bf[nb][ks] = *(const s16x8*)(Bs + r * 128 + ((ch ^ (r & 7)) << 4));
        }
      }
      __builtin_amdgcn_s_setprio(1);
      #pragma unroll
      for (int mb = 0; mb < 4; mb++)
        #pragma unroll
        for (int nb = 0; nb < 2; nb++)
          #pragma unroll
          for (int ks = 0; ks < 2; ks++)
            acc[mb][nb] = __builtin_amdgcn_mfma_f32_32x32x16_bf16(
                af[mb][ks], bf[nb][ks], acc[mb][nb], 0, 0, 0);
      __builtin_amdgcn_s_setprio(0);
    }
    __syncthreads();
  }

  // epilogue: fp32 + bias; C/D layout col=lane&31, row=(reg&3)+8*(reg>>2)+4*lh
  #pragma unroll
  for (int mb = 0; mb < 4; mb++) {
    #pragma unroll
    for (int nb = 0; nb < 2; nb++) {
      int n = n0 + WN * 64 + nb * 32 + l31;
      float bv = bias[n];
      #pragma unroll
      for (int reg = 0; reg < 16; reg++) {
        int m = m0 + WM * 128 + mb * 32 + (reg & 3) + 8 * (reg >> 2) + 4 * lh;
        C[(size_t)m * VOCAB + n] = acc[mb][nb][reg] + bv;
      }
    }
  }
}

// ---------------- fp32 GEMM fallback (small-ws path only) ----------------
#define BM 128
#define BN 128
#define BKF 32
#define LDT (BM + 4)
__global__ __launch_bounds__(256) void k_gemm32(
    const float* __restrict__ A, const float* __restrict__ Bw,
    const float* __restrict__ bias, float* __restrict__ C, int N) {
  __shared__ float As[BKF * LDT];
  __shared__ float Bs[BKF * LDT];
  int tid = threadIdx.x;
  int tx = tid & 15, ty = tid >> 4;
  int n0 = blockIdx.x * BN;
  int m0 = blockIdx.y * BM;
  float acc[8][8];
  #pragma unroll
  for (int i = 0; i < 8; i++)
    #pragma unroll
    for (int j = 0; j < 8; j++) acc[i][j] = 0.f;
  for (int k0 = 0; k0 < E; k0 += BKF) {
    #pragma unroll
    for (int i = 0; i < 4; i++) {
      int f = i * 256 + tid;
      int ml = f >> 3, c4 = f & 7;
      float4 va = *(const float4*)(A + (size_t)(m0 + ml) * E + k0 + c4 * 4);
      As[(c4 * 4 + 0) * LDT + ml] = va.x;
      As[(c4 * 4 + 1) * LDT + ml] = va.y;
      As[(c4 * 4 + 2) * LDT + ml] = va.z;
      As[(c4 * 4 + 3) * LDT + ml] = va.w;
    }
    #pragma unroll
    for (int i = 0; i < 4; i++) {
      int f = i * 256 + tid;
      int kk = f >> 5, c4 = f & 31;
      float4 vb = *(const float4*)(Bw + (size_t)(k0 + kk) * N + n0 + c4 * 4);
      *(float4*)(Bs + kk * LDT + c4 * 4) = vb;
    }
    __syncthreads();
    #pragma unroll
    for (int kk = 0; kk < BKF; kk++) {
      const float4* ar = (const float4*)(As + kk * LDT);
      const float4* br = (const float4*)(Bs + kk * LDT);
      float4 a0 = ar[ty * 2], a1 = ar[ty * 2 + 1];
      float4 b0 = br[tx * 2], b1 = br[tx * 2 + 1];
      float av[8] = {a0.x, a0.y, a0.z, a0.w, a1.x, a1.y, a1.z, a1.w};
      float bvv[8] = {b0.x, b0.y, b0.z, b0.w, b1.x, b1.y, b1.z, b1.w};
      #pragma unroll
      for (int i = 0; i < 8; i++)
        #pragma unroll
        for (int j = 0; j < 8; j++)
          acc[i][j] = fmaf(av[i], bvv[j], acc[i][j]);
    }
    __syncthreads();
  }
  int mbase = m0 + ty * 8;
  int nbase = n0 + tx * 8;
  #pragma unroll
  for (int i = 0; i < 8; i++) {
    float* crow = C + (size_t)(mbase + i) * N + nbase;
    #pragma unroll
    for (int j = 0; j < 8; j++) crow[j] = acc[i][j] + bias[nbase + j];
  }
}

// ---------------- fused: MFMA flash attention + wt(fc_w) ----------------
// attn: ballot-gated max reduce — thread-local max + __any decides the (rare)
// rescale; the 4-shfl row-max reduce runs only inside that branch. Semantics
// identical (any-lane-exceeds <=> row-max-exceeds; branch is wave-uniform).
__global__ __launch_bounds__(256) void k_attn_wt(
    const unsigned short* __restrict__ qb, const unsigned short* __restrict__ kb,
    const unsigned short* __restrict__ vtb, unsigned short* __restrict__ o,
    const float* __restrict__ fcw, unsigned short* __restrict__ fcwt) {
  __shared__ __align__(16) char lds[49152];  // K dbuf 16K | Vt dbuf 16K | P 4x4K
  int gid = blockIdx.x;
  int tid = threadIdx.x;

  if (gid >= 512) {
    int idx = gid - 512;
    wt_body(fcw, fcwt, VOCAB, (idx % 500) * 64, (idx / 500) * 64, tid,
            (float(*)[65])lds);
    return;
  }

  int qt = 15 - (gid >> 5);
  int bh = gid & 31;
  int b = bh >> 4, hh = bh & 15;
  int lane = tid & 63, wv = tid >> 6;
  int fr = lane & 15, fq = lane >> 4;
  int q0 = qt * 128;
  int qw0 = q0 + wv * 32;
  const char* Kg = (const char*)(kb + (size_t)bh * T * 64);
  const char* Vg = (const char*)(vtb + (size_t)bh * 64 * T);
  char* Pl = lds + 32768 + wv * 4096;

  s16x8 qf[2][2];
  #pragma unroll
  for (int g = 0; g < 2; g++) {
    const unsigned short* Qg = qb + ((size_t)bh * T + qw0 + g * 16) * 64;
    qf[g][0] = *(const s16x8*)(Qg + (size_t)fr * 64 + fq * 8);
    qf[g][1] = *(const s16x8*)(Qg + (size_t)fr * 64 + 32 + fq * 8);
  }

  f32x4 po[2][4];
  float mrow[2][4], lrow[2][4];
  #pragma unroll
  for (int g = 0; g < 2; g++)
    #pragma unroll
    for (int j = 0; j < 4; j++) {
      po[g][j] = (f32x4){0.f, 0.f, 0.f, 0.f};
      mrow[g][j] = -1e30f; lrow[g][j] = 0.f;
    }

  int ntiles = qt * 2 + 2;
  int i0 = tid, i1 = tid + 256;
  int sr0 = i0 >> 3, sc0 = ((i0 & 7) ^ (sr0 & 7)) << 4;
  int sr1 = i1 >> 3, sc1 = ((i1 & 7) ^ (sr1 & 7)) << 4;

  {
    gload16(Kg + (size_t)sr0 * 128 + sc0, lds + i0 * 16);
    gload16(Kg + (size_t)sr1 * 128 + sc1, lds + i1 * 16);
    gload16(Vg + (size_t)sr0 * (T * 2) + sc0, lds + 16384 + i0 * 16);
    gload16(Vg + (size_t)sr1 * (T * 2) + sc1, lds + 16384 + i1 * 16);
  }
  __syncthreads();
  int cur = 0;

  for (int kt = 0; kt < ntiles; kt++) {
    int kv0 = kt * 64;
    if (kt + 1 < ntiles) {
      size_t kvn = (size_t)(kv0 + 64);
      char* kd = lds + (cur ^ 1) * 8192;
      char* vd = lds + 16384 + (cur ^ 1) * 8192;
      gload16(Kg + (kvn + sr0) * 128 + sc0, kd + i0 * 16);
      gload16(Kg + (kvn + sr1) * 128 + sc1, kd + i1 * 16);
      gload16(Vg + (size_t)sr0 * (T * 2) + kvn * 2 + sc0, vd + i0 * 16);
      gload16(Vg + (size_t)sr1 * (T * 2) + kvn * 2 + sc1, vd + i1 * 16);
    }
    const char* Kt = lds + cur * 8192;
    const char* Vt = lds + 16384 + cur * 8192;

    f32x4 s[2][4];
    #pragma unroll
    for (int ni = 0; ni < 4; ni++) {
      int r = ni * 16 + fr;
      s16x8 kf0 = *(const s16x8*)(Kt + r * 128 + ((fq ^ (r & 7)) << 4));
      s16x8 kf1 = *(const s16x8*)(Kt + r * 128 + (((4 + fq) ^ (r & 7)) << 4));
      #pragma unroll
      for (int g = 0; g < 2; g++) {
        s[g][ni] = (f32x4){0.f, 0.f, 0.f, 0.f};
        s[g][ni] = __builtin_amdgcn_mfma_f32_16x16x32_bf16(qf[g][0], kf0, s[g][ni], 0, 0, 0);
        s[g][ni] = __builtin_amdgcn_mfma_f32_16x16x32_bf16(qf[g][1], kf1, s[g][ni], 0, 0, 0);
      }
    }

    #pragma unroll
    for (int g = 0; g < 2; g++) {
      int qw = qw0 + g * 16;
      bool needm = (kv0 + 63 > qw);
      #pragma unroll
      for (int jj = 0; jj < 4; jj++) {
        int row = qw + fq * 4 + jj;
        float tm = -1e30f;
        #pragma unroll
        for (int ni = 0; ni < 4; ni++) {
          float val = s[g][ni][jj] * 0.125f;
          if (needm) { int col = kv0 + ni * 16 + fr; if (col > row) val = -1e30f; }
          s[g][ni][jj] = val;
          tm = fmaxf(tm, val);
        }
        // ballot-gated: full row-max reduce only when some lane exceeds m+8
        if (__any(tm > mrow[g][jj] + 8.f)) {
          float twm = tm;
          #pragma unroll
          for (int mk = 1; mk < 16; mk <<= 1) twm = fmaxf(twm, __shfl_xor(twm, mk));
          float nm = fmaxf(mrow[g][jj], twm);
          float corr = __expf(mrow[g][jj] - nm);
          mrow[g][jj] = nm;
          #pragma unroll
          for (int ni = 0; ni < 4; ni++) po[g][ni][jj] *= corr;
          lrow[g][jj] *= corr;
        }
        float mref = mrow[g][jj];
        float rs = 0.f;
        #pragma unroll
        for (int ni = 0; ni < 4; ni++) {
          float pv = __expf(s[g][ni][jj] - mref);
          s[g][ni][jj] = pv;
          rs += pv;
        }
        #pragma unroll
        for (int mk = 1; mk < 16; mk <<= 1) rs += __shfl_xor(rs, mk);
        lrow[g][jj] += rs;
      }
    }

    asm volatile("s_waitcnt lgkmcnt(0)" ::: "memory");
    #pragma unroll
    for (int g = 0; g < 2; g++) {
      char* Pg = Pl + g * 2048;
      #pragma unroll
      for (int ni = 0; ni < 4; ni++) {
        int col = ni * 16 + fr;
        #pragma unroll
        for (int jj = 0; jj < 4; jj++) {
          int qq = fq * 4 + jj;
          *(unsigned short*)(Pg + qq * 128 + (((col >> 3) ^ (qq & 7)) << 4) +
                             (col & 7) * 2) = f2bf(s[g][ni][jj]);
        }
      }
    }
    asm volatile("s_waitcnt lgkmcnt(0)" ::: "memory");

    s16x8 pa[2][2];
    #pragma unroll
    for (int g = 0; g < 2; g++) {
      const char* Pg = Pl + g * 2048;
      pa[g][0] = *(const s16x8*)(Pg + fr * 128 + ((fq ^ (fr & 7)) << 4));
      pa[g][1] = *(const s16x8*)(Pg + fr * 128 + (((4 + fq) ^ (fr & 7)) << 4));
    }
    #pragma unroll
    for (int ni = 0; ni < 4; ni++) {
      int r = ni * 16 + fr;
      s16x8 vf0 = *(const s16x8*)(Vt + r * 128 + ((fq ^ (r & 7)) << 4));
      s16x8 vf1 = *(const s16x8*)(Vt + r * 128 + (((4 + fq) ^ (r & 7)) << 4));
      #pragma unroll
      for (int g = 0; g < 2; g++) {
        po[g][ni] = __builtin_amdgcn_mfma_f32_16x16x32_bf16(pa[g][0], vf0, po[g][ni], 0, 0, 0);
        po[g][ni] = __builtin_amdgcn_mfma_f32_16x16x32_bf16(pa[g][1], vf1, po[g][ni], 0, 0, 0);
      }
    }
    __syncthreads();
    cur ^= 1;
  }

  #pragma unroll
  for (int g = 0; g < 2; g++)
    #pragma unroll
    for (int jj = 0; jj < 4; jj++) {
      float inv = 1.f / lrow[g][jj];
      int row = qw0 + g * 16 + fq * 4 + jj;
      unsigned short* orow = o + ((size_t)(b * T + row)) * E + hh * 64;
      #pragma unroll
      for (int ni = 0; ni < 4; ni++)
        orow[ni * 16 + fr] = f2bf(po[g][ni][jj] * inv);
    }
}

extern "C" void kernel_launch(void* const* d_in, const int* in_sizes, int n_in,
                              void* d_out, int out_size, void* d_ws, size_t ws_size,
                              hipStream_t stream) {
  const int*   x      = (const int*)d_in[0];
  const float* tok    = (const float*)d_in[1];
  const float* pos    = (const float*)d_in[2];
  const float* qkv_w  = (const float*)d_in[3];
  const float* qkv_b  = (const float*)d_in[4];
  const float* proj_w = (const float*)d_in[5];
  const float* proj_b = (const float*)d_in[6];
  const float* fc_w   = (const float*)d_in[7];
  const float* fc_b   = (const float*)d_in[8];
  float* out = (float*)d_out;
  float* ws  = (float*)d_ws;

  // scratch layout in d_out (fully overwritten by fc at the end)
  unsigned short* hb      = (unsigned short*)out;                     // 2,097,152 f
  unsigned short* qkv_wt  = (unsigned short*)(out + 2097152);         // 1,572,864 f
  unsigned short* qbuf    = (unsigned short*)(out + 3670016);         // 2,097,152 f
  unsigned short* kbuf    = (unsigned short*)(out + 5767168);         // 2,097,152 f
  unsigned short* vtbuf   = (unsigned short*)(out + 7864320);         // 2,097,152 f
  unsigned short* aob     = (unsigned short*)(out + 9961472);         // 2,097,152 f
  unsigned short* proj_wt = (unsigned short*)(out + 12058624);        //   524,288 f

  const size_t WS_FAST = (size_t)(2097152 + 16384000) * 4;

  k_pre<<<5120, 256, 0, stream>>>(x, tok, pos, hb, qkv_w, qkv_wt, proj_w, proj_wt);
  k_qkv<<<192, 512, 0, stream>>>(hb, qkv_wt, qkv_b, qbuf, kbuf, vtbuf);

  if (ws_size >= WS_FAST) {
    unsigned short* h2b   = (unsigned short*)ws;
    unsigned short* fc_wt = (unsigned short*)(ws + 2097152);
    k_attn_wt<<<8512, 256, 0, stream>>>(qbuf, kbuf, vtbuf, aob, fc_w, fc_wt);
    k_bgemm<2><<<dim3(E / 128, M / 128), 256, 0, stream>>>(
        aob, proj_wt, proj_b, nullptr, E, h2b);
    k_fc<<<dim3((M / 256) * (VOCAB / 256)), 512, 0, stream>>>(
        h2b, fc_wt, fc_b, out);
  } else {
    float* h2 = ws;
    k_attn_wt<<<512, 256, 0, stream>>>(qbuf, kbuf, vtbuf, aob, nullptr, nullptr);
    k_bgemm<0><<<dim3(E / 128, M / 128), 256, 0, stream>>>(
        aob, proj_wt, proj_b, h2, E, nullptr);
    k_gemm32<<<dim3(VOCAB / BN, M / BM), 256, 0, stream>>>(
        h2, fc_w, fc_b, out, VOCAB);
  }
}

// Round 17
// 492.435 us; speedup vs baseline: 1.0018x; 1.0018x over previous
//
#include <hip/hip_runtime.h>

#define BATCH 2
#define T 2048
#define E 1024
#define NH 16
#define HD 64
#define M (BATCH*T)   // 4096
#define K3 (3*E)      // 3072
#define VOCAB 32000

typedef __attribute__((ext_vector_type(8))) short s16x8;
typedef __attribute__((ext_vector_type(4))) short s16x4;
typedef __attribute__((ext_vector_type(4))) float f32x4;
typedef __attribute__((ext_vector_type(16))) float f32x16;

__device__ inline unsigned short f2bf(float f) {
  union { float f; unsigned u; } x; x.f = f;
  unsigned r = x.u + 0x7fffu + ((x.u >> 16) & 1u);   // RNE
  return (unsigned short)(r >> 16);
}

__device__ inline void gload16(const void* g, void* l) {
  __builtin_amdgcn_global_load_lds(
      (const __attribute__((address_space(1))) unsigned int*)g,
      (__attribute__((address_space(3))) unsigned int*)l, 16, 0, 0);
}

// ---- weight transpose+convert body: W[1024][N] f32 -> Wt[N][1024] bf16 ----
__device__ inline void wt_body(const float* __restrict__ W,
    unsigned short* __restrict__ Wt, int N, int n0, int k0, int t,
    float (*tile)[65]) {
  int kl = t >> 2, c = t & 3;
  #pragma unroll
  for (int i = 0; i < 4; i++) {
    float4 v4 = *(const float4*)(W + (size_t)(k0 + kl) * N + n0 + c * 16 + i * 4);
    tile[kl][c * 16 + i * 4 + 0] = v4.x;
    tile[kl][c * 16 + i * 4 + 1] = v4.y;
    tile[kl][c * 16 + i * 4 + 2] = v4.z;
    tile[kl][c * 16 + i * 4 + 3] = v4.w;
  }
  __syncthreads();
  #pragma unroll
  for (int j = 0; j < 2; j++) {
    int idx = t + j * 256;
    int nl = idx >> 3, kq = (idx & 7) * 8;
    s16x8 o;
    #pragma unroll
    for (int i = 0; i < 8; i++) o[i] = (short)f2bf(tile[kq + i][nl]);
    *(s16x8*)(Wt + (size_t)(n0 + nl) * 1024 + k0 + kq) = o;
  }
}

// ---------------- k_pre: embed + wt(qkv_w) + wt(proj_w) fused ----------------
__global__ __launch_bounds__(256) void k_pre(const int* __restrict__ x,
    const float* __restrict__ tok, const float* __restrict__ pos,
    unsigned short* __restrict__ hb,
    const float* __restrict__ qkvw, unsigned short* __restrict__ qkvwt,
    const float* __restrict__ projw, unsigned short* __restrict__ projwt) {
  __shared__ __align__(16) float tile[64][65];
  int gid = blockIdx.x, t = threadIdx.x;
  if (gid < 4096) {
    int row = gid;
    int tt = row & (T - 1);
    int tokid = x[row];
    float4 a = ((const float4*)(tok + (size_t)tokid * E))[t];
    float4 p = ((const float4*)(pos + (size_t)tt * E))[t];
    s16x4 o;
    o[0] = (short)f2bf(a.x + p.x); o[1] = (short)f2bf(a.y + p.y);
    o[2] = (short)f2bf(a.z + p.z); o[3] = (short)f2bf(a.w + p.w);
    *(s16x4*)(hb + (size_t)row * E + t * 4) = o;
    return;
  }
  if (gid < 4864) {
    int idx = gid - 4096;
    wt_body(qkvw, qkvwt, K3, (idx % 48) * 64, (idx / 48) * 64, t, tile);
    return;
  }
  int idx = gid - 4864;
  wt_body(projw, projwt, E, (idx % 16) * 64, (idx / 16) * 64, t, tile);
}

// ---------------- bf16 MFMA GEMM 128x128 (m97 structure) ----------------
// MODE 0: fp32 C + bias.  MODE 2: bf16 C + bias.  (used for proj + fallback)
template<int MODE>
__global__ __launch_bounds__(256) void k_bgemm(
    const unsigned short* __restrict__ A, const unsigned short* __restrict__ Bt,
    const float* __restrict__ bias, float* __restrict__ C, int N,
    unsigned short* __restrict__ Cb) {
  __shared__ char lds[16384];
  char* As = lds;
  char* Bs = lds + 8192;
  int tid = threadIdx.x;
  int lane = tid & 63;
  int wv = tid >> 6;
  int wm = wv >> 1, wn = wv & 1;
  int n0 = blockIdx.x * 128, m0 = blockIdx.y * 128;
  int fr = lane & 15, fq = lane >> 4;

  f32x4 acc[4][4];
  #pragma unroll
  for (int i = 0; i < 4; i++)
    #pragma unroll
    for (int j = 0; j < 4; j++) acc[i][j] = (f32x4){0.f, 0.f, 0.f, 0.f};

  int p0 = tid * 16, p1 = tid * 16 + 4096;
  int r0 = p0 >> 6, c0 = p0 & 63;
  int r1 = p1 >> 6, c1 = p1 & 63;
  int cs0 = c0 ^ (((r0 >> 1) & 3) << 4);
  int cs1 = c1 ^ (((r1 >> 1) & 3) << 4);
  const char* ga0 = (const char*)(A + (size_t)(m0 + r0) * 1024) + cs0;
  const char* ga1 = (const char*)(A + (size_t)(m0 + r1) * 1024) + cs1;
  const char* gb0 = (const char*)(Bt + (size_t)(n0 + r0) * 1024) + cs0;
  const char* gb1 = (const char*)(Bt + (size_t)(n0 + r1) * 1024) + cs1;

  int aoff[4], boff[4];
  #pragma unroll
  for (int i = 0; i < 4; i++) {
    int ra = wm * 64 + i * 16 + fr;
    aoff[i] = ra * 64 + ((fq * 16) ^ (((ra >> 1) & 3) << 4));
    int rb = wn * 64 + i * 16 + fr;
    boff[i] = rb * 64 + ((fq * 16) ^ (((rb >> 1) & 3) << 4));
  }

  for (int kb = 0; kb < 2048; kb += 64) {
    gload16(ga0 + kb, As + p0);
    gload16(ga1 + kb, As + p1);
    gload16(gb0 + kb, Bs + p0);
    gload16(gb1 + kb, Bs + p1);
    __syncthreads();
    s16x8 af[4], bfr[4];
    #pragma unroll
    for (int i = 0; i < 4; i++) af[i] = *(const s16x8*)(As + aoff[i]);
    #pragma unroll
    for (int i = 0; i < 4; i++) bfr[i] = *(const s16x8*)(Bs + boff[i]);
    #pragma unroll
    for (int mi = 0; mi < 4; mi++)
      #pragma unroll
      for (int ni = 0; ni < 4; ni++)
        acc[mi][ni] = __builtin_amdgcn_mfma_f32_16x16x32_bf16(
            af[mi], bfr[ni], acc[mi][ni], 0, 0, 0);
    __syncthreads();
  }

  #pragma unroll
  for (int mi = 0; mi < 4; mi++) {
    #pragma unroll
    for (int ni = 0; ni < 4; ni++) {
      #pragma unroll
      for (int j = 0; j < 4; j++) {
        int m = m0 + wm * 64 + mi * 16 + fq * 4 + j;
        int n = n0 + wn * 64 + ni * 16 + fr;
        float val = acc[mi][ni][j] + bias[n];
        if (MODE == 0) C[(size_t)m * N + n] = val;
        else           Cb[(size_t)m * 1024 + n] = f2bf(val);
      }
    }
  }
}

// ---------------- qkv GEMM: R4-256² structure + scatter epilogue ----------------
__global__ __launch_bounds__(512, 2) void k_qkv(
    const unsigned short* __restrict__ A, const unsigned short* __restrict__ Bt,
    const float* __restrict__ bias,
    unsigned short* __restrict__ qo, unsigned short* __restrict__ ko,
    unsigned short* __restrict__ vo) {
  __shared__ __align__(16) char lds[131072];
  int tid = threadIdx.x, lane = tid & 63, wv = tid >> 6;
  int WM = wv >> 2, WN = wv & 3;
  int fr = lane & 15, fq = lane >> 4;

  int bid = blockIdx.x;                 // 192 blocks
  int wg = (bid & 7) * 24 + (bid >> 3); // bijective (192 % 8 == 0)
  int m0 = (wg % 16) * 256;
  int n0 = (wg / 16) * 256;

  const char* gA[4]; const char* gB[4]; int lo[4];
  #pragma unroll
  for (int j = 0; j < 4; j++) {
    int i = tid + j * 512;
    int r = i >> 3, c = i & 7;
    int cc = c ^ (r & 7);
    gA[j] = (const char*)A + ((size_t)(m0 + r) * 1024 + cc * 8) * 2;
    gB[j] = (const char*)Bt + ((size_t)(n0 + r) * 1024 + cc * 8) * 2;
    lo[j] = i * 16;
  }

  f32x4 acc[8][4];
  #pragma unroll
  for (int i = 0; i < 8; i++)
    #pragma unroll
    for (int j = 0; j < 4; j++) acc[i][j] = (f32x4){0.f, 0.f, 0.f, 0.f};

  #pragma unroll
  for (int j = 0; j < 4; j++) {
    gload16(gA[j], lds + lo[j]);
    gload16(gB[j], lds + 65536 + lo[j]);
  }
  __syncthreads();

  for (int t = 0; t < 16; t++) {
    int cur = t & 1;
    if (t + 1 < 16) {
      int kb = (t + 1) * 128;
      int nxt = cur ^ 1;
      #pragma unroll
      for (int j = 0; j < 4; j++) {
        gload16(gA[j] + kb, lds + nxt * 32768 + lo[j]);
        gload16(gB[j] + kb, lds + 65536 + nxt * 32768 + lo[j]);
      }
    }
    const char* As = lds + cur * 32768;
    const char* Bs = lds + 65536 + cur * 32768;
    #pragma unroll
    for (int kh = 0; kh < 2; kh++) {
      s16x8 af[8], bf[4];
      #pragma unroll
      for (int mi = 0; mi < 8; mi++) {
        int r = WM * 128 + mi * 16 + fr;
        af[mi] = *(const s16x8*)(As + r * 128 + (((kh * 4 + fq) ^ (r & 7)) << 4));
      }
      #pragma unroll
      for (int ni = 0; ni < 4; ni++) {
        int r = WN * 64 + ni * 16 + fr;
        bf[ni] = *(const s16x8*)(Bs + r * 128 + (((kh * 4 + fq) ^ (r & 7)) << 4));
      }
      __builtin_amdgcn_s_setprio(1);
      #pragma unroll
      for (int mi = 0; mi < 8; mi++)
        #pragma unroll
        for (int ni = 0; ni < 4; ni++)
          acc[mi][ni] = __builtin_amdgcn_mfma_f32_16x16x32_bf16(
              af[mi], bf[ni], acc[mi][ni], 0, 0, 0);
      __builtin_amdgcn_s_setprio(0);
    }
    __syncthreads();
  }

  #pragma unroll
  for (int mi = 0; mi < 8; mi++) {
    #pragma unroll
    for (int ni = 0; ni < 4; ni++) {
      int n = n0 + WN * 64 + ni * 16 + fr;
      int which = n >> 10;
      int e = n & (E - 1);
      int hh = e >> 6, d = e & 63;
      int mb = m0 + WM * 128 + mi * 16 + fq * 4;
      int b = mb >> 11, tt0 = mb & (T - 1);
      float bv = bias[n];
      if (which == 2) {
        s16x4 pk;
        #pragma unroll
        for (int j = 0; j < 4; j++) pk[j] = (short)f2bf(acc[mi][ni][j] + bv);
        *(s16x4*)(vo + ((size_t)(b * NH + hh) * 64 + d) * T + tt0) = pk;
      } else {
        unsigned short* dst = (which == 0) ? qo : ko;
        #pragma unroll
        for (int j = 0; j < 4; j++)
          dst[((size_t)(b * NH + hh) * T + tt0 + j) * 64 + d] =
              f2bf(acc[mi][ni][j] + bv);
      }
    }
  }
}

// ---------------- fc GEMM: R4 schedule + 32x32x16 MFMA fragments ----------------
// Same staging/sync/swizzle as the x4-reproduced R4 kernel; only the fragment
// shape changes: per K=32 step, 16 MFMA 32x32x16 (8.07 cyc, 2495 TF ceiling)
// replaces 32 MFMA 16x16x32 (4.85 cyc, 2075 TF) — 17% less MFMA-pipe time,
// identical ds_read count. A-frag: m=lane&31, k=(lane>>5)*8+j (analog of the
// verified 16x16 mapping). C/D: col=lane&31, row=(reg&3)+8*(reg>>2)+4*(lane>>5)
// (m74/m101-verified). absmax is the layout checker.
__global__ __launch_bounds__(512, 2) void k_fc(
    const unsigned short* __restrict__ A, const unsigned short* __restrict__ Bt,
    const float* __restrict__ bias, float* __restrict__ C) {
  __shared__ __align__(16) char lds[131072];  // As0|As1 @0,32K ; Bs0|Bs1 @64K,96K
  int tid = threadIdx.x, lane = tid & 63, wv = tid >> 6;
  int WM = wv >> 2, WN = wv & 3;              // 2M x 4N waves, per-wave 128x64
  int l31 = lane & 31, lh = lane >> 5;

  int bid = blockIdx.x;
  int wg = (bid & 7) * 250 + (bid >> 3);
  int m0 = (wg & 15) * 256;
  int n0 = (wg >> 4) * 256;

  const char* gA[4]; const char* gB[4]; int lo[4];
  #pragma unroll
  for (int j = 0; j < 4; j++) {
    int i = tid + j * 512;
    int r = i >> 3, c = i & 7;
    int cc = c ^ (r & 7);
    gA[j] = (const char*)A + ((size_t)(m0 + r) * 1024 + cc * 8) * 2;
    gB[j] = (const char*)Bt + ((size_t)(n0 + r) * 1024 + cc * 8) * 2;
    lo[j] = i * 16;
  }

  f32x16 acc[4][2];
  #pragma unroll
  for (int i = 0; i < 4; i++)
    #pragma unroll
    for (int j = 0; j < 2; j++)
      #pragma unroll
      for (int e = 0; e < 16; e++) acc[i][j][e] = 0.f;

  #pragma unroll
  for (int j = 0; j < 4; j++) {
    gload16(gA[j], lds + lo[j]);
    gload16(gB[j], lds + 65536 + lo[j]);
  }
  __syncthreads();

  for (int t = 0; t < 16; t++) {
    int cur = t & 1;
    if (t + 1 < 16) {
      int kb = (t + 1) * 128;
      int nxt = cur ^ 1;
      #pragma unroll
      for (int j = 0; j < 4; j++) {
        gload16(gA[j] + kb, lds + nxt * 32768 + lo[j]);
        gload16(gB[j] + kb, lds + 65536 + nxt * 32768 + lo[j]);
      }
    }
    const char* As = lds + cur * 32768;
    const char* Bs = lds + 65536 + cur * 32768;
    #pragma unroll
    for (int kh = 0; kh < 2; kh++) {
      s16x8 af[4][2], bf[2][2];
      #pragma unroll
      for (int mb = 0; mb < 4; mb++) {
        int r = WM * 128 + mb * 32 + l31;
        #pragma unroll
        for (int ks = 0; ks < 2; ks++) {
          int ch = kh * 4 + ks * 2 + lh;
          af[mb][ks] = *(const s16x8*)(As + r * 128 + ((ch ^ (r & 7)) << 4));
        }
      }
      #pragma unroll
      for (int nb = 0; nb < 2; nb++) {
        int r = WN * 64 + nb * 32 + l31;
        #pragma unroll
        for (int ks = 0; ks < 2; ks++) {
          int ch = kh * 4 + ks * 2 + lh;
          bf[nb][ks] = *(const s16x8*)(Bs + r * 128 + ((ch ^ (r & 7)) << 4));
        }
      }
      __builtin_amdgcn_s_setprio(1);
      #pragma unroll
      for (int mb = 0; mb < 4; mb++)
        #pragma unroll
        for (int nb = 0; nb < 2; nb++)
          #pragma unroll
          for (int ks = 0; ks < 2; ks++)
            acc[mb][nb] = __builtin_amdgcn_mfma_f32_32x32x16_bf16(
                af[mb][ks], bf[nb][ks], acc[mb][nb], 0, 0, 0);
      __builtin_amdgcn_s_setprio(0);
    }
    __syncthreads();
  }

  // epilogue: fp32 + bias; C/D layout col=lane&31, row=(reg&3)+8*(reg>>2)+4*lh
  #pragma unroll
  for (int mb = 0; mb < 4; mb++) {
    #pragma unroll
    for (int nb = 0; nb < 2; nb++) {
      int n = n0 + WN * 64 + nb * 32 + l31;
      float bv = bias[n];
      #pragma unroll
      for (int reg = 0; reg < 16; reg++) {
        int m = m0 + WM * 128 + mb * 32 + (reg & 3) + 8 * (reg >> 2) + 4 * lh;
        C[(size_t)m * VOCAB + n] = acc[mb][nb][reg] + bv;
      }
    }
  }
}

// ---------------- fp32 GEMM fallback (small-ws path only) ----------------
#define BM 128
#define BN 128
#define BKF 32
#define LDT (BM + 4)
__global__ __launch_bounds__(256) void k_gemm32(
    const float* __restrict__ A, const float* __restrict__ Bw,
    const float* __restrict__ bias, float* __restrict__ C, int N) {
  __shared__ float As[BKF * LDT];
  __shared__ float Bs[BKF * LDT];
  int tid = threadIdx.x;
  int tx = tid & 15, ty = tid >> 4;
  int n0 = blockIdx.x * BN;
  int m0 = blockIdx.y * BM;
  float acc[8][8];
  #pragma unroll
  for (int i = 0; i < 8; i++)
    #pragma unroll
    for (int j = 0; j < 8; j++) acc[i][j] = 0.f;
  for (int k0 = 0; k0 < E; k0 += BKF) {
    #pragma unroll
    for (int i = 0; i < 4; i++) {
      int f = i * 256 + tid;
      int ml = f >> 3, c4 = f & 7;
      float4 va = *(const float4*)(A + (size_t)(m0 + ml) * E + k0 + c4 * 4);
      As[(c4 * 4 + 0) * LDT + ml] = va.x;
      As[(c4 * 4 + 1) * LDT + ml] = va.y;
      As[(c4 * 4 + 2) * LDT + ml] = va.z;
      As[(c4 * 4 + 3) * LDT + ml] = va.w;
    }
    #pragma unroll
    for (int i = 0; i < 4; i++) {
      int f = i * 256 + tid;
      int kk = f >> 5, c4 = f & 31;
      float4 vb = *(const float4*)(Bw + (size_t)(k0 + kk) * N + n0 + c4 * 4);
      *(float4*)(Bs + kk * LDT + c4 * 4) = vb;
    }
    __syncthreads();
    #pragma unroll
    for (int kk = 0; kk < BKF; kk++) {
      const float4* ar = (const float4*)(As + kk * LDT);
      const float4* br = (const float4*)(Bs + kk * LDT);
      float4 a0 = ar[ty * 2], a1 = ar[ty * 2 + 1];
      float4 b0 = br[tx * 2], b1 = br[tx * 2 + 1];
      float av[8] = {a0.x, a0.y, a0.z, a0.w, a1.x, a1.y, a1.z, a1.w};
      float bvv[8] = {b0.x, b0.y, b0.z, b0.w, b1.x, b1.y, b1.z, b1.w};
      #pragma unroll
      for (int i = 0; i < 8; i++)
        #pragma unroll
        for (int j = 0; j < 8; j++)
          acc[i][j] = fmaf(av[i], bvv[j], acc[i][j]);
    }
    __syncthreads();
  }
  int mbase = m0 + ty * 8;
  int nbase = n0 + tx * 8;
  #pragma unroll
  for (int i = 0; i < 8; i++) {
    float* crow = C + (size_t)(mbase + i) * N + nbase;
    #pragma unroll
    for (int j = 0; j < 8; j++) crow[j] = acc[i][j] + bias[nbase + j];
  }
}

// ---------------- fused: MFMA flash attention + wt(fc_w) ----------------
// attn: ballot-gated max reduce — thread-local max + __any decides the (rare)
// rescale; the 4-shfl row-max reduce runs only inside that branch. Semantics
// identical (any-lane-exceeds <=> row-max-exceeds; branch is wave-uniform).
__global__ __launch_bounds__(256) void k_attn_wt(
    const unsigned short* __restrict__ qb, const unsigned short* __restrict__ kb,
    const unsigned short* __restrict__ vtb, unsigned short* __restrict__ o,
    const float* __restrict__ fcw, unsigned short* __restrict__ fcwt) {
  __shared__ __align__(16) char lds[49152];  // K dbuf 16K | Vt dbuf 16K | P 4x4K
  int gid = blockIdx.x;
  int tid = threadIdx.x;

  if (gid >= 512) {
    int idx = gid - 512;
    wt_body(fcw, fcwt, VOCAB, (idx % 500) * 64, (idx / 500) * 64, tid,
            (float(*)[65])lds);
    return;
  }

  int qt = 15 - (gid >> 5);
  int bh = gid & 31;
  int b = bh >> 4, hh = bh & 15;
  int lane = tid & 63, wv = tid >> 6;
  int fr = lane & 15, fq = lane >> 4;
  int q0 = qt * 128;
  int qw0 = q0 + wv * 32;
  const char* Kg = (const char*)(kb + (size_t)bh * T * 64);
  const char* Vg = (const char*)(vtb + (size_t)bh * 64 * T);
  char* Pl = lds + 32768 + wv * 4096;

  s16x8 qf[2][2];
  #pragma unroll
  for (int g = 0; g < 2; g++) {
    const unsigned short* Qg = qb + ((size_t)bh * T + qw0 + g * 16) * 64;
    qf[g][0] = *(const s16x8*)(Qg + (size_t)fr * 64 + fq * 8);
    qf[g][1] = *(const s16x8*)(Qg + (size_t)fr * 64 + 32 + fq * 8);
  }

  f32x4 po[2][4];
  float mrow[2][4], lrow[2][4];
  #pragma unroll
  for (int g = 0; g < 2; g++)
    #pragma unroll
    for (int j = 0; j < 4; j++) {
      po[g][j] = (f32x4){0.f, 0.f, 0.f, 0.f};
      mrow[g][j] = -1e30f; lrow[g][j] = 0.f;
    }

  int ntiles = qt * 2 + 2;
  int i0 = tid, i1 = tid + 256;
  int sr0 = i0 >> 3, sc0 = ((i0 & 7) ^ (sr0 & 7)) << 4;
  int sr1 = i1 >> 3, sc1 = ((i1 & 7) ^ (sr1 & 7)) << 4;

  {
    gload16(Kg + (size_t)sr0 * 128 + sc0, lds + i0 * 16);
    gload16(Kg + (size_t)sr1 * 128 + sc1, lds + i1 * 16);
    gload16(Vg + (size_t)sr0 * (T * 2) + sc0, lds + 16384 + i0 * 16);
    gload16(Vg + (size_t)sr1 * (T * 2) + sc1, lds + 16384 + i1 * 16);
  }
  __syncthreads();
  int cur = 0;

  for (int kt = 0; kt < ntiles; kt++) {
    int kv0 = kt * 64;
    if (kt + 1 < ntiles) {
      size_t kvn = (size_t)(kv0 + 64);
      char* kd = lds + (cur ^ 1) * 8192;
      char* vd = lds + 16384 + (cur ^ 1) * 8192;
      gload16(Kg + (kvn + sr0) * 128 + sc0, kd + i0 * 16);
      gload16(Kg + (kvn + sr1) * 128 + sc1, kd + i1 * 16);
      gload16(Vg + (size_t)sr0 * (T * 2) + kvn * 2 + sc0, vd + i0 * 16);
      gload16(Vg + (size_t)sr1 * (T * 2) + kvn * 2 + sc1, vd + i1 * 16);
    }
    const char* Kt = lds + cur * 8192;
    const char* Vt = lds + 16384 + cur * 8192;

    f32x4 s[2][4];
    #pragma unroll
    for (int ni = 0; ni < 4; ni++) {
      int r = ni * 16 + fr;
      s16x8 kf0 = *(const s16x8*)(Kt + r * 128 + ((fq ^ (r & 7)) << 4));
      s16x8 kf1 = *(const s16x8*)(Kt + r * 128 + (((4 + fq) ^ (r & 7)) << 4));
      #pragma unroll
      for (int g = 0; g < 2; g++) {
        s[g][ni] = (f32x4){0.f, 0.f, 0.f, 0.f};
        s[g][ni] = __builtin_amdgcn_mfma_f32_16x16x32_bf16(qf[g][0], kf0, s[g][ni], 0, 0, 0);
        s[g][ni] = __builtin_amdgcn_mfma_f32_16x16x32_bf16(qf[g][1], kf1, s[g][ni], 0, 0, 0);
      }
    }

    #pragma unroll
    for (int g = 0; g < 2; g++) {
      int qw = qw0 + g * 16;
      bool needm = (kv0 + 63 > qw);
      #pragma unroll
      for (int jj = 0; jj < 4; jj++) {
        int row = qw + fq * 4 + jj;
        float tm = -1e30f;
        #pragma unroll
        for (int ni = 0; ni < 4; ni++) {
          float val = s[g][ni][jj] * 0.125f;
          if (needm) { int col = kv0 + ni * 16 + fr; if (col > row) val = -1e30f; }
          s[g][ni][jj] = val;
          tm = fmaxf(tm, val);
        }
        // ballot-gated: full row-max reduce only when some lane exceeds m+8
        if (__any(tm > mrow[g][jj] + 8.f)) {
          float twm = tm;
          #pragma unroll
          for (int mk = 1; mk < 16; mk <<= 1) twm = fmaxf(twm, __shfl_xor(twm, mk));
          float nm = fmaxf(mrow[g][jj], twm);
          float corr = __expf(mrow[g][jj] - nm);
          mrow[g][jj] = nm;
          #pragma unroll
          for (int ni = 0; ni < 4; ni++) po[g][ni][jj] *= corr;
          lrow[g][jj] *= corr;
        }
        float mref = mrow[g][jj];
        float rs = 0.f;
        #pragma unroll
        for (int ni = 0; ni < 4; ni++) {
          float pv = __expf(s[g][ni][jj] - mref);
          s[g][ni][jj] = pv;
          rs += pv;
        }
        #pragma unroll
        for (int mk = 1; mk < 16; mk <<= 1) rs += __shfl_xor(rs, mk);
        lrow[g][jj] += rs;
      }
    }

    asm volatile("s_waitcnt lgkmcnt(0)" ::: "memory");
    #pragma unroll
    for (int g = 0; g < 2; g++) {
      char* Pg = Pl + g * 2048;
      #pragma unroll
      for (int ni = 0; ni < 4; ni++) {
        int col = ni * 16 + fr;
        #pragma unroll
        for (int jj = 0; jj < 4; jj++) {
          int qq = fq * 4 + jj;
          *(unsigned short*)(Pg + qq * 128 + (((col >> 3) ^ (qq & 7)) << 4) +
                             (col & 7) * 2) = f2bf(s[g][ni][jj]);
        }
      }
    }
    asm volatile("s_waitcnt lgkmcnt(0)" ::: "memory");

    s16x8 pa[2][2];
    #pragma unroll
    for (int g = 0; g < 2; g++) {
      const char* Pg = Pl + g * 2048;
      pa[g][0] = *(const s16x8*)(Pg + fr * 128 + ((fq ^ (fr & 7)) << 4));
      pa[g][1] = *(const s16x8*)(Pg + fr * 128 + (((4 + fq) ^ (fr & 7)) << 4));
    }
    #pragma unroll
    for (int ni = 0; ni < 4; ni++) {
      int r = ni * 16 + fr;
      s16x8 vf0 = *(const s16x8*)(Vt + r * 128 + ((fq ^ (r & 7)) << 4));
      s16x8 vf1 = *(const s16x8*)(Vt + r * 128 + (((4 + fq) ^ (r & 7)) << 4));
      #pragma unroll
      for (int g = 0; g < 2; g++) {
        po[g][ni] = __builtin_amdgcn_mfma_f32_16x16x32_bf16(pa[g][0], vf0, po[g][ni], 0, 0, 0);
        po[g][ni] = __builtin_amdgcn_mfma_f32_16x16x32_bf16(pa[g][1], vf1, po[g][ni], 0, 0, 0);
      }
    }
    __syncthreads();
    cur ^= 1;
  }

  #pragma unroll
  for (int g = 0; g < 2; g++)
    #pragma unroll
    for (int jj = 0; jj < 4; jj++) {
      float inv = 1.f / lrow[g][jj];
      int row = qw0 + g * 16 + fq * 4 + jj;
      unsigned short* orow = o + ((size_t)(b * T + row)) * E + hh * 64;
      #pragma unroll
      for (int ni = 0; ni < 4; ni++)
        orow[ni * 16 + fr] = f2bf(po[g][ni][jj] * inv);
    }
}

extern "C" void kernel_launch(void* const* d_in, const int* in_sizes, int n_in,
                              void* d_out, int out_size, void* d_ws, size_t ws_size,
                              hipStream_t stream) {
  const int*   x      = (const int*)d_in[0];
  const float* tok    = (const float*)d_in[1];
  const float* pos    = (const float*)d_in[2];
  const float* qkv_w  = (const float*)d_in[3];
  const float* qkv_b  = (const float*)d_in[4];
  const float* proj_w = (const float*)d_in[5];
  const float* proj_b = (const float*)d_in[6];
  const float* fc_w   = (const float*)d_in[7];
  const float* fc_b   = (const float*)d_in[8];
  float* out = (float*)d_out;
  float* ws  = (float*)d_ws;

  // scratch layout in d_out (fully overwritten by fc at the end)
  unsigned short* hb      = (unsigned short*)out;                     // 2,097,152 f
  unsigned short* qkv_wt  = (unsigned short*)(out + 2097152);         // 1,572,864 f
  unsigned short* qbuf    = (unsigned short*)(out + 3670016);         // 2,097,152 f
  unsigned short* kbuf    = (unsigned short*)(out + 5767168);         // 2,097,152 f
  unsigned short* vtbuf   = (unsigned short*)(out + 7864320);         // 2,097,152 f
  unsigned short* aob     = (unsigned short*)(out + 9961472);         // 2,097,152 f
  unsigned short* proj_wt = (unsigned short*)(out + 12058624);        //   524,288 f

  const size_t WS_FAST = (size_t)(2097152 + 16384000) * 4;

  k_pre<<<5120, 256, 0, stream>>>(x, tok, pos, hb, qkv_w, qkv_wt, proj_w, proj_wt);
  k_qkv<<<192, 512, 0, stream>>>(hb, qkv_wt, qkv_b, qbuf, kbuf, vtbuf);

  if (ws_size >= WS_FAST) {
    unsigned short* h2b   = (unsigned short*)ws;
    unsigned short* fc_wt = (unsigned short*)(ws + 2097152);
    k_attn_wt<<<8512, 256, 0, stream>>>(qbuf, kbuf, vtbuf, aob, fc_w, fc_wt);
    k_bgemm<2><<<dim3(E / 128, M / 128), 256, 0, stream>>>(
        aob, proj_wt, proj_b, nullptr, E, h2b);
    k_fc<<<dim3((M / 256) * (VOCAB / 256)), 512, 0, stream>>>(
        h2b, fc_wt, fc_b, out);
  } else {
    float* h2 = ws;
    k_attn_wt<<<512, 256, 0, stream>>>(qbuf, kbuf, vtbuf, aob, nullptr, nullptr);
    k_bgemm<0><<<dim3(E / 128, M / 128), 256, 0, stream>>>(
        aob, proj_wt, proj_b, h2, E, nullptr);
    k_gemm32<<<dim3(VOCAB / BN, M / BM), 256, 0, stream>>>(
        h2, fc_w, fc_b, out, VOCAB);
  }
}

// Round 18
// 478.925 us; speedup vs baseline: 1.0300x; 1.0282x over previous
//
#include <hip/hip_runtime.h>

#define BATCH 2
#define T 2048
#define E 1024
#define NH 16
#define HD 64
#define M (BATCH*T)   // 4096
#define K3 (3*E)      // 3072
#define VOCAB 32000

typedef __attribute__((ext_vector_type(8))) short s16x8;
typedef __attribute__((ext_vector_type(4))) short s16x4;
typedef __attribute__((ext_vector_type(4))) float f32x4;

__device__ inline unsigned short f2bf(float f) {
  union { float f; unsigned u; } x; x.f = f;
  unsigned r = x.u + 0x7fffu + ((x.u >> 16) & 1u);   // RNE
  return (unsigned short)(r >> 16);
}

__device__ inline void gload16(const void* g, void* l) {
  __builtin_amdgcn_global_load_lds(
      (const __attribute__((address_space(1))) unsigned int*)g,
      (__attribute__((address_space(3))) unsigned int*)l, 16, 0, 0);
}

// ---- weight transpose+convert body: W[1024][N] f32 -> Wt[N][1024] bf16 ----
__device__ inline void wt_body(const float* __restrict__ W,
    unsigned short* __restrict__ Wt, int N, int n0, int k0, int t,
    float (*tile)[65]) {
  int kl = t >> 2, c = t & 3;
  #pragma unroll
  for (int i = 0; i < 4; i++) {
    float4 v4 = *(const float4*)(W + (size_t)(k0 + kl) * N + n0 + c * 16 + i * 4);
    tile[kl][c * 16 + i * 4 + 0] = v4.x;
    tile[kl][c * 16 + i * 4 + 1] = v4.y;
    tile[kl][c * 16 + i * 4 + 2] = v4.z;
    tile[kl][c * 16 + i * 4 + 3] = v4.w;
  }
  __syncthreads();
  #pragma unroll
  for (int j = 0; j < 2; j++) {
    int idx = t + j * 256;
    int nl = idx >> 3, kq = (idx & 7) * 8;
    s16x8 o;
    #pragma unroll
    for (int i = 0; i < 8; i++) o[i] = (short)f2bf(tile[kq + i][nl]);
    *(s16x8*)(Wt + (size_t)(n0 + nl) * 1024 + k0 + kq) = o;
  }
}

// ---------------- k_pre: embed + wt(qkv_w) + wt(proj_w) fused ----------------
__global__ __launch_bounds__(256) void k_pre(const int* __restrict__ x,
    const float* __restrict__ tok, const float* __restrict__ pos,
    unsigned short* __restrict__ hb,
    const float* __restrict__ qkvw, unsigned short* __restrict__ qkvwt,
    const float* __restrict__ projw, unsigned short* __restrict__ projwt) {
  __shared__ __align__(16) float tile[64][65];
  int gid = blockIdx.x, t = threadIdx.x;
  if (gid < 4096) {
    int row = gid;
    int tt = row & (T - 1);
    int tokid = x[row];
    float4 a = ((const float4*)(tok + (size_t)tokid * E))[t];
    float4 p = ((const float4*)(pos + (size_t)tt * E))[t];
    s16x4 o;
    o[0] = (short)f2bf(a.x + p.x); o[1] = (short)f2bf(a.y + p.y);
    o[2] = (short)f2bf(a.z + p.z); o[3] = (short)f2bf(a.w + p.w);
    *(s16x4*)(hb + (size_t)row * E + t * 4) = o;
    return;
  }
  if (gid < 4864) {
    int idx = gid - 4096;
    wt_body(qkvw, qkvwt, K3, (idx % 48) * 64, (idx / 48) * 64, t, tile);
    return;
  }
  int idx = gid - 4864;
  wt_body(projw, projwt, E, (idx % 16) * 64, (idx / 16) * 64, t, tile);
}

// ---------------- bf16 MFMA GEMM 128x128 (m97 structure) ----------------
// MODE 0: fp32 C + bias.  MODE 2: bf16 C + bias.  (used for proj + fallback)
template<int MODE>
__global__ __launch_bounds__(256) void k_bgemm(
    const unsigned short* __restrict__ A, const unsigned short* __restrict__ Bt,
    const float* __restrict__ bias, float* __restrict__ C, int N,
    unsigned short* __restrict__ Cb) {
  __shared__ char lds[16384];
  char* As = lds;
  char* Bs = lds + 8192;
  int tid = threadIdx.x;
  int lane = tid & 63;
  int wv = tid >> 6;
  int wm = wv >> 1, wn = wv & 1;
  int n0 = blockIdx.x * 128, m0 = blockIdx.y * 128;
  int fr = lane & 15, fq = lane >> 4;

  f32x4 acc[4][4];
  #pragma unroll
  for (int i = 0; i < 4; i++)
    #pragma unroll
    for (int j = 0; j < 4; j++) acc[i][j] = (f32x4){0.f, 0.f, 0.f, 0.f};

  int p0 = tid * 16, p1 = tid * 16 + 4096;
  int r0 = p0 >> 6, c0 = p0 & 63;
  int r1 = p1 >> 6, c1 = p1 & 63;
  int cs0 = c0 ^ (((r0 >> 1) & 3) << 4);
  int cs1 = c1 ^ (((r1 >> 1) & 3) << 4);
  const char* ga0 = (const char*)(A + (size_t)(m0 + r0) * 1024) + cs0;
  const char* ga1 = (const char*)(A + (size_t)(m0 + r1) * 1024) + cs1;
  const char* gb0 = (const char*)(Bt + (size_t)(n0 + r0) * 1024) + cs0;
  const char* gb1 = (const char*)(Bt + (size_t)(n0 + r1) * 1024) + cs1;

  int aoff[4], boff[4];
  #pragma unroll
  for (int i = 0; i < 4; i++) {
    int ra = wm * 64 + i * 16 + fr;
    aoff[i] = ra * 64 + ((fq * 16) ^ (((ra >> 1) & 3) << 4));
    int rb = wn * 64 + i * 16 + fr;
    boff[i] = rb * 64 + ((fq * 16) ^ (((rb >> 1) & 3) << 4));
  }

  for (int kb = 0; kb < 2048; kb += 64) {
    gload16(ga0 + kb, As + p0);
    gload16(ga1 + kb, As + p1);
    gload16(gb0 + kb, Bs + p0);
    gload16(gb1 + kb, Bs + p1);
    __syncthreads();
    s16x8 af[4], bfr[4];
    #pragma unroll
    for (int i = 0; i < 4; i++) af[i] = *(const s16x8*)(As + aoff[i]);
    #pragma unroll
    for (int i = 0; i < 4; i++) bfr[i] = *(const s16x8*)(Bs + boff[i]);
    #pragma unroll
    for (int mi = 0; mi < 4; mi++)
      #pragma unroll
      for (int ni = 0; ni < 4; ni++)
        acc[mi][ni] = __builtin_amdgcn_mfma_f32_16x16x32_bf16(
            af[mi], bfr[ni], acc[mi][ni], 0, 0, 0);
    __syncthreads();
  }

  #pragma unroll
  for (int mi = 0; mi < 4; mi++) {
    #pragma unroll
    for (int ni = 0; ni < 4; ni++) {
      #pragma unroll
      for (int j = 0; j < 4; j++) {
        int m = m0 + wm * 64 + mi * 16 + fq * 4 + j;
        int n = n0 + wn * 64 + ni * 16 + fr;
        float val = acc[mi][ni][j] + bias[n];
        if (MODE == 0) C[(size_t)m * N + n] = val;
        else           Cb[(size_t)m * 1024 + n] = f2bf(val);
      }
    }
  }
}

// ---------------- qkv GEMM: R4-256² structure + scatter epilogue ----------------
__global__ __launch_bounds__(512, 2) void k_qkv(
    const unsigned short* __restrict__ A, const unsigned short* __restrict__ Bt,
    const float* __restrict__ bias,
    unsigned short* __restrict__ qo, unsigned short* __restrict__ ko,
    unsigned short* __restrict__ vo) {
  __shared__ __align__(16) char lds[131072];
  int tid = threadIdx.x, lane = tid & 63, wv = tid >> 6;
  int WM = wv >> 2, WN = wv & 3;
  int fr = lane & 15, fq = lane >> 4;

  int bid = blockIdx.x;                 // 192 blocks
  int wg = (bid & 7) * 24 + (bid >> 3); // bijective (192 % 8 == 0)
  int m0 = (wg % 16) * 256;
  int n0 = (wg / 16) * 256;

  const char* gA[4]; const char* gB[4]; int lo[4];
  #pragma unroll
  for (int j = 0; j < 4; j++) {
    int i = tid + j * 512;
    int r = i >> 3, c = i & 7;
    int cc = c ^ (r & 7);
    gA[j] = (const char*)A + ((size_t)(m0 + r) * 1024 + cc * 8) * 2;
    gB[j] = (const char*)Bt + ((size_t)(n0 + r) * 1024 + cc * 8) * 2;
    lo[j] = i * 16;
  }

  f32x4 acc[8][4];
  #pragma unroll
  for (int i = 0; i < 8; i++)
    #pragma unroll
    for (int j = 0; j < 4; j++) acc[i][j] = (f32x4){0.f, 0.f, 0.f, 0.f};

  #pragma unroll
  for (int j = 0; j < 4; j++) {
    gload16(gA[j], lds + lo[j]);
    gload16(gB[j], lds + 65536 + lo[j]);
  }
  __syncthreads();

  for (int t = 0; t < 16; t++) {
    int cur = t & 1;
    if (t + 1 < 16) {
      int kb = (t + 1) * 128;
      int nxt = cur ^ 1;
      #pragma unroll
      for (int j = 0; j < 4; j++) {
        gload16(gA[j] + kb, lds + nxt * 32768 + lo[j]);
        gload16(gB[j] + kb, lds + 65536 + nxt * 32768 + lo[j]);
      }
    }
    const char* As = lds + cur * 32768;
    const char* Bs = lds + 65536 + cur * 32768;
    #pragma unroll
    for (int kh = 0; kh < 2; kh++) {
      s16x8 af[8], bf[4];
      #pragma unroll
      for (int mi = 0; mi < 8; mi++) {
        int r = WM * 128 + mi * 16 + fr;
        af[mi] = *(const s16x8*)(As + r * 128 + (((kh * 4 + fq) ^ (r & 7)) << 4));
      }
      #pragma unroll
      for (int ni = 0; ni < 4; ni++) {
        int r = WN * 64 + ni * 16 + fr;
        bf[ni] = *(const s16x8*)(Bs + r * 128 + (((kh * 4 + fq) ^ (r & 7)) << 4));
      }
      __builtin_amdgcn_s_setprio(1);
      #pragma unroll
      for (int mi = 0; mi < 8; mi++)
        #pragma unroll
        for (int ni = 0; ni < 4; ni++)
          acc[mi][ni] = __builtin_amdgcn_mfma_f32_16x16x32_bf16(
              af[mi], bf[ni], acc[mi][ni], 0, 0, 0);
      __builtin_amdgcn_s_setprio(0);
    }
    __syncthreads();
  }

  #pragma unroll
  for (int mi = 0; mi < 8; mi++) {
    #pragma unroll
    for (int ni = 0; ni < 4; ni++) {
      int n = n0 + WN * 64 + ni * 16 + fr;
      int which = n >> 10;
      int e = n & (E - 1);
      int hh = e >> 6, d = e & 63;
      int mb = m0 + WM * 128 + mi * 16 + fq * 4;
      int b = mb >> 11, tt0 = mb & (T - 1);
      float bv = bias[n];
      if (which == 2) {
        s16x4 pk;
        #pragma unroll
        for (int j = 0; j < 4; j++) pk[j] = (short)f2bf(acc[mi][ni][j] + bv);
        *(s16x4*)(vo + ((size_t)(b * NH + hh) * 64 + d) * T + tt0) = pk;
      } else {
        unsigned short* dst = (which == 0) ? qo : ko;
        #pragma unroll
        for (int j = 0; j < 4; j++)
          dst[((size_t)(b * NH + hh) * T + tt0 + j) * 64 + d] =
              f2bf(acc[mi][ni][j] + bv);
      }
    }
  }
}

// ---------------- fc GEMM: R4-exact 16x16x32 (x4 reproduced at 321-327 us) ----------------
// R17 lesson: 32x32 fragments are a STRUCTURAL 4-way LDS conflict in row-major
// 128B-row tiles (bank = f(chunk only); 32 rows share 8 chunk slots) — no
// chunk-XOR fixes it. 16x16 (16 rows/chunk-set -> 2-way = free, m136) stays.
__global__ __launch_bounds__(512, 2) void k_fc(
    const unsigned short* __restrict__ A, const unsigned short* __restrict__ Bt,
    const float* __restrict__ bias, float* __restrict__ C) {
  __shared__ __align__(16) char lds[131072];  // As0|As1 @0,32K ; Bs0|Bs1 @64K,96K
  int tid = threadIdx.x, lane = tid & 63, wv = tid >> 6;
  int WM = wv >> 2, WN = wv & 3;              // 2M x 4N waves, per-wave 128x64
  int fr = lane & 15, fq = lane >> 4;

  int bid = blockIdx.x;
  int wg = (bid & 7) * 250 + (bid >> 3);
  int m0 = (wg & 15) * 256;
  int n0 = (wg >> 4) * 256;

  const char* gA[4]; const char* gB[4]; int lo[4];
  #pragma unroll
  for (int j = 0; j < 4; j++) {
    int i = tid + j * 512;
    int r = i >> 3, c = i & 7;
    int cc = c ^ (r & 7);
    gA[j] = (const char*)A + ((size_t)(m0 + r) * 1024 + cc * 8) * 2;
    gB[j] = (const char*)Bt + ((size_t)(n0 + r) * 1024 + cc * 8) * 2;
    lo[j] = i * 16;
  }

  f32x4 acc[8][4];
  #pragma unroll
  for (int i = 0; i < 8; i++)
    #pragma unroll
    for (int j = 0; j < 4; j++) acc[i][j] = (f32x4){0.f, 0.f, 0.f, 0.f};

  #pragma unroll
  for (int j = 0; j < 4; j++) {
    gload16(gA[j], lds + lo[j]);
    gload16(gB[j], lds + 65536 + lo[j]);
  }
  __syncthreads();

  for (int t = 0; t < 16; t++) {
    int cur = t & 1;
    if (t + 1 < 16) {
      int kb = (t + 1) * 128;
      int nxt = cur ^ 1;
      #pragma unroll
      for (int j = 0; j < 4; j++) {
        gload16(gA[j] + kb, lds + nxt * 32768 + lo[j]);
        gload16(gB[j] + kb, lds + 65536 + nxt * 32768 + lo[j]);
      }
    }
    const char* As = lds + cur * 32768;
    const char* Bs = lds + 65536 + cur * 32768;
    #pragma unroll
    for (int kh = 0; kh < 2; kh++) {
      s16x8 af[8], bf[4];
      #pragma unroll
      for (int mi = 0; mi < 8; mi++) {
        int r = WM * 128 + mi * 16 + fr;
        af[mi] = *(const s16x8*)(As + r * 128 + (((kh * 4 + fq) ^ (r & 7)) << 4));
      }
      #pragma unroll
      for (int ni = 0; ni < 4; ni++) {
        int r = WN * 64 + ni * 16 + fr;
        bf[ni] = *(const s16x8*)(Bs + r * 128 + (((kh * 4 + fq) ^ (r & 7)) << 4));
      }
      __builtin_amdgcn_s_setprio(1);
      #pragma unroll
      for (int mi = 0; mi < 8; mi++)
        #pragma unroll
        for (int ni = 0; ni < 4; ni++)
          acc[mi][ni] = __builtin_amdgcn_mfma_f32_16x16x32_bf16(
              af[mi], bf[ni], acc[mi][ni], 0, 0, 0);
      __builtin_amdgcn_s_setprio(0);
    }
    __syncthreads();
  }

  #pragma unroll
  for (int mi = 0; mi < 8; mi++) {
    #pragma unroll
    for (int ni = 0; ni < 4; ni++) {
      int n = n0 + WN * 64 + ni * 16 + fr;
      float bv = bias[n];
      #pragma unroll
      for (int j = 0; j < 4; j++) {
        int m = m0 + WM * 128 + mi * 16 + fq * 4 + j;
        C[(size_t)m * VOCAB + n] = acc[mi][ni][j] + bv;
      }
    }
  }
}

// ---------------- fp32 GEMM fallback (small-ws path only) ----------------
#define BM 128
#define BN 128
#define BKF 32
#define LDT (BM + 4)
__global__ __launch_bounds__(256) void k_gemm32(
    const float* __restrict__ A, const float* __restrict__ Bw,
    const float* __restrict__ bias, float* __restrict__ C, int N) {
  __shared__ float As[BKF * LDT];
  __shared__ float Bs[BKF * LDT];
  int tid = threadIdx.x;
  int tx = tid & 15, ty = tid >> 4;
  int n0 = blockIdx.x * BN;
  int m0 = blockIdx.y * BM;
  float acc[8][8];
  #pragma unroll
  for (int i = 0; i < 8; i++)
    #pragma unroll
    for (int j = 0; j < 8; j++) acc[i][j] = 0.f;
  for (int k0 = 0; k0 < E; k0 += BKF) {
    #pragma unroll
    for (int i = 0; i < 4; i++) {
      int f = i * 256 + tid;
      int ml = f >> 3, c4 = f & 7;
      float4 va = *(const float4*)(A + (size_t)(m0 + ml) * E + k0 + c4 * 4);
      As[(c4 * 4 + 0) * LDT + ml] = va.x;
      As[(c4 * 4 + 1) * LDT + ml] = va.y;
      As[(c4 * 4 + 2) * LDT + ml] = va.z;
      As[(c4 * 4 + 3) * LDT + ml] = va.w;
    }
    #pragma unroll
    for (int i = 0; i < 4; i++) {
      int f = i * 256 + tid;
      int kk = f >> 5, c4 = f & 31;
      float4 vb = *(const float4*)(Bw + (size_t)(k0 + kk) * N + n0 + c4 * 4);
      *(float4*)(Bs + kk * LDT + c4 * 4) = vb;
    }
    __syncthreads();
    #pragma unroll
    for (int kk = 0; kk < BKF; kk++) {
      const float4* ar = (const float4*)(As + kk * LDT);
      const float4* br = (const float4*)(Bs + kk * LDT);
      float4 a0 = ar[ty * 2], a1 = ar[ty * 2 + 1];
      float4 b0 = br[tx * 2], b1 = br[tx * 2 + 1];
      float av[8] = {a0.x, a0.y, a0.z, a0.w, a1.x, a1.y, a1.z, a1.w};
      float bvv[8] = {b0.x, b0.y, b0.z, b0.w, b1.x, b1.y, b1.z, b1.w};
      #pragma unroll
      for (int i = 0; i < 8; i++)
        #pragma unroll
        for (int j = 0; j < 8; j++)
          acc[i][j] = fmaf(av[i], bvv[j], acc[i][j]);
    }
    __syncthreads();
  }
  int mbase = m0 + ty * 8;
  int nbase = n0 + tx * 8;
  #pragma unroll
  for (int i = 0; i < 8; i++) {
    float* crow = C + (size_t)(mbase + i) * N + nbase;
    #pragma unroll
    for (int j = 0; j < 8; j++) crow[j] = acc[i][j] + bias[nbase + j];
  }
}

// ---------------- fused: MFMA flash attention + wt(fc_w) ----------------
// attn: QBLK=128, shared K/V fragments across q-row groups, ballot-gated
// defer-max (R17-proven tail win). blocks 512+: fc weight transpose.
__global__ __launch_bounds__(256) void k_attn_wt(
    const unsigned short* __restrict__ qb, const unsigned short* __restrict__ kb,
    const unsigned short* __restrict__ vtb, unsigned short* __restrict__ o,
    const float* __restrict__ fcw, unsigned short* __restrict__ fcwt) {
  __shared__ __align__(16) char lds[49152];  // K dbuf 16K | Vt dbuf 16K | P 4x4K
  int gid = blockIdx.x;
  int tid = threadIdx.x;

  if (gid >= 512) {
    int idx = gid - 512;
    wt_body(fcw, fcwt, VOCAB, (idx % 500) * 64, (idx / 500) * 64, tid,
            (float(*)[65])lds);
    return;
  }

  int qt = 15 - (gid >> 5);
  int bh = gid & 31;
  int b = bh >> 4, hh = bh & 15;
  int lane = tid & 63, wv = tid >> 6;
  int fr = lane & 15, fq = lane >> 4;
  int q0 = qt * 128;
  int qw0 = q0 + wv * 32;
  const char* Kg = (const char*)(kb + (size_t)bh * T * 64);
  const char* Vg = (const char*)(vtb + (size_t)bh * 64 * T);
  char* Pl = lds + 32768 + wv * 4096;

  s16x8 qf[2][2];
  #pragma unroll
  for (int g = 0; g < 2; g++) {
    const unsigned short* Qg = qb + ((size_t)bh * T + qw0 + g * 16) * 64;
    qf[g][0] = *(const s16x8*)(Qg + (size_t)fr * 64 + fq * 8);
    qf[g][1] = *(const s16x8*)(Qg + (size_t)fr * 64 + 32 + fq * 8);
  }

  f32x4 po[2][4];
  float mrow[2][4], lrow[2][4];
  #pragma unroll
  for (int g = 0; g < 2; g++)
    #pragma unroll
    for (int j = 0; j < 4; j++) {
      po[g][j] = (f32x4){0.f, 0.f, 0.f, 0.f};
      mrow[g][j] = -1e30f; lrow[g][j] = 0.f;
    }

  int ntiles = qt * 2 + 2;
  int i0 = tid, i1 = tid + 256;
  int sr0 = i0 >> 3, sc0 = ((i0 & 7) ^ (sr0 & 7)) << 4;
  int sr1 = i1 >> 3, sc1 = ((i1 & 7) ^ (sr1 & 7)) << 4;

  {
    gload16(Kg + (size_t)sr0 * 128 + sc0, lds + i0 * 16);
    gload16(Kg + (size_t)sr1 * 128 + sc1, lds + i1 * 16);
    gload16(Vg + (size_t)sr0 * (T * 2) + sc0, lds + 16384 + i0 * 16);
    gload16(Vg + (size_t)sr1 * (T * 2) + sc1, lds + 16384 + i1 * 16);
  }
  __syncthreads();
  int cur = 0;

  for (int kt = 0; kt < ntiles; kt++) {
    int kv0 = kt * 64;
    if (kt + 1 < ntiles) {
      size_t kvn = (size_t)(kv0 + 64);
      char* kd = lds + (cur ^ 1) * 8192;
      char* vd = lds + 16384 + (cur ^ 1) * 8192;
      gload16(Kg + (kvn + sr0) * 128 + sc0, kd + i0 * 16);
      gload16(Kg + (kvn + sr1) * 128 + sc1, kd + i1 * 16);
      gload16(Vg + (size_t)sr0 * (T * 2) + kvn * 2 + sc0, vd + i0 * 16);
      gload16(Vg + (size_t)sr1 * (T * 2) + kvn * 2 + sc1, vd + i1 * 16);
    }
    const char* Kt = lds + cur * 8192;
    const char* Vt = lds + 16384 + cur * 8192;

    f32x4 s[2][4];
    #pragma unroll
    for (int ni = 0; ni < 4; ni++) {
      int r = ni * 16 + fr;
      s16x8 kf0 = *(const s16x8*)(Kt + r * 128 + ((fq ^ (r & 7)) << 4));
      s16x8 kf1 = *(const s16x8*)(Kt + r * 128 + (((4 + fq) ^ (r & 7)) << 4));
      #pragma unroll
      for (int g = 0; g < 2; g++) {
        s[g][ni] = (f32x4){0.f, 0.f, 0.f, 0.f};
        s[g][ni] = __builtin_amdgcn_mfma_f32_16x16x32_bf16(qf[g][0], kf0, s[g][ni], 0, 0, 0);
        s[g][ni] = __builtin_amdgcn_mfma_f32_16x16x32_bf16(qf[g][1], kf1, s[g][ni], 0, 0, 0);
      }
    }

    #pragma unroll
    for (int g = 0; g < 2; g++) {
      int qw = qw0 + g * 16;
      bool needm = (kv0 + 63 > qw);
      #pragma unroll
      for (int jj = 0; jj < 4; jj++) {
        int row = qw + fq * 4 + jj;
        float tm = -1e30f;
        #pragma unroll
        for (int ni = 0; ni < 4; ni++) {
          float val = s[g][ni][jj] * 0.125f;
          if (needm) { int col = kv0 + ni * 16 + fr; if (col > row) val = -1e30f; }
          s[g][ni][jj] = val;
          tm = fmaxf(tm, val);
        }
        if (__any(tm > mrow[g][jj] + 8.f)) {
          float twm = tm;
          #pragma unroll
          for (int mk = 1; mk < 16; mk <<= 1) twm = fmaxf(twm, __shfl_xor(twm, mk));
          float nm = fmaxf(mrow[g][jj], twm);
          float corr = __expf(mrow[g][jj] - nm);
          mrow[g][jj] = nm;
          #pragma unroll
          for (int ni = 0; ni < 4; ni++) po[g][ni][jj] *= corr;
          lrow[g][jj] *= corr;
        }
        float mref = mrow[g][jj];
        float rs = 0.f;
        #pragma unroll
        for (int ni = 0; ni < 4; ni++) {
          float pv = __expf(s[g][ni][jj] - mref);
          s[g][ni][jj] = pv;
          rs += pv;
        }
        #pragma unroll
        for (int mk = 1; mk < 16; mk <<= 1) rs += __shfl_xor(rs, mk);
        lrow[g][jj] += rs;
      }
    }

    asm volatile("s_waitcnt lgkmcnt(0)" ::: "memory");
    #pragma unroll
    for (int g = 0; g < 2; g++) {
      char* Pg = Pl + g * 2048;
      #pragma unroll
      for (int ni = 0; ni < 4; ni++) {
        int col = ni * 16 + fr;
        #pragma unroll
        for (int jj = 0; jj < 4; jj++) {
          int qq = fq * 4 + jj;
          *(unsigned short*)(Pg + qq * 128 + (((col >> 3) ^ (qq & 7)) << 4) +
                             (col & 7) * 2) = f2bf(s[g][ni][jj]);
        }
      }
    }
    asm volatile("s_waitcnt lgkmcnt(0)" ::: "memory");

    s16x8 pa[2][2];
    #pragma unroll
    for (int g = 0; g < 2; g++) {
      const char* Pg = Pl + g * 2048;
      pa[g][0] = *(const s16x8*)(Pg + fr * 128 + ((fq ^ (fr & 7)) << 4));
      pa[g][1] = *(const s16x8*)(Pg + fr * 128 + (((4 + fq) ^ (fr & 7)) << 4));
    }
    #pragma unroll
    for (int ni = 0; ni < 4; ni++) {
      int r = ni * 16 + fr;
      s16x8 vf0 = *(const s16x8*)(Vt + r * 128 + ((fq ^ (r & 7)) << 4));
      s16x8 vf1 = *(const s16x8*)(Vt + r * 128 + (((4 + fq) ^ (r & 7)) << 4));
      #pragma unroll
      for (int g = 0; g < 2; g++) {
        po[g][ni] = __builtin_amdgcn_mfma_f32_16x16x32_bf16(pa[g][0], vf0, po[g][ni], 0, 0, 0);
        po[g][ni] = __builtin_amdgcn_mfma_f32_16x16x32_bf16(pa[g][1], vf1, po[g][ni], 0, 0, 0);
      }
    }
    __syncthreads();
    cur ^= 1;
  }

  #pragma unroll
  for (int g = 0; g < 2; g++)
    #pragma unroll
    for (int jj = 0; jj < 4; jj++) {
      float inv = 1.f / lrow[g][jj];
      int row = qw0 + g * 16 + fq * 4 + jj;
      unsigned short* orow = o + ((size_t)(b * T + row)) * E + hh * 64;
      #pragma unroll
      for (int ni = 0; ni < 4; ni++)
        orow[ni * 16 + fr] = f2bf(po[g][ni][jj] * inv);
    }
}

extern "C" void kernel_launch(void* const* d_in, const int* in_sizes, int n_in,
                              void* d_out, int out_size, void* d_ws, size_t ws_size,
                              hipStream_t stream) {
  const int*   x      = (const int*)d_in[0];
  const float* tok    = (const float*)d_in[1];
  const float* pos    = (const float*)d_in[2];
  const float* qkv_w  = (const float*)d_in[3];
  const float* qkv_b  = (const float*)d_in[4];
  const float* proj_w = (const float*)d_in[5];
  const float* proj_b = (const float*)d_in[6];
  const float* fc_w   = (const float*)d_in[7];
  const float* fc_b   = (const float*)d_in[8];
  float* out = (float*)d_out;
  float* ws  = (float*)d_ws;

  // scratch layout in d_out (fully overwritten by fc at the end)
  unsigned short* hb      = (unsigned short*)out;                     // 2,097,152 f
  unsigned short* qkv_wt  = (unsigned short*)(out + 2097152);         // 1,572,864 f
  unsigned short* qbuf    = (unsigned short*)(out + 3670016);         // 2,097,152 f
  unsigned short* kbuf    = (unsigned short*)(out + 5767168);         // 2,097,152 f
  unsigned short* vtbuf   = (unsigned short*)(out + 7864320);         // 2,097,152 f
  unsigned short* aob     = (unsigned short*)(out + 9961472);         // 2,097,152 f
  unsigned short* proj_wt = (unsigned short*)(out + 12058624);        //   524,288 f

  const size_t WS_FAST = (size_t)(2097152 + 16384000) * 4;

  k_pre<<<5120, 256, 0, stream>>>(x, tok, pos, hb, qkv_w, qkv_wt, proj_w, proj_wt);
  k_qkv<<<192, 512, 0, stream>>>(hb, qkv_wt, qkv_b, qbuf, kbuf, vtbuf);

  if (ws_size >= WS_FAST) {
    unsigned short* h2b   = (unsigned short*)ws;
    unsigned short* fc_wt = (unsigned short*)(ws + 2097152);
    k_attn_wt<<<8512, 256, 0, stream>>>(qbuf, kbuf, vtbuf, aob, fc_w, fc_wt);
    k_bgemm<2><<<dim3(E / 128, M / 128), 256, 0, stream>>>(
        aob, proj_wt, proj_b, nullptr, E, h2b);
    k_fc<<<dim3((M / 256) * (VOCAB / 256)), 512, 0, stream>>>(
        h2b, fc_wt, fc_b, out);
  } else {
    float* h2 = ws;
    k_attn_wt<<<512, 256, 0, stream>>>(qbuf, kbuf, vtbuf, aob, nullptr, nullptr);
    k_bgemm<0><<<dim3(E / 128, M / 128), 256, 0, stream>>>(
        aob, proj_wt, proj_b, h2, E, nullptr);
    k_gemm32<<<dim3(VOCAB / BN, M / BM), 256, 0, stream>>>(
        h2, fc_w, fc_b, out, VOCAB);
  }
}

// Round 19
// 476.086 us; speedup vs baseline: 1.0362x; 1.0060x over previous
//
#include <hip/hip_runtime.h>

#define BATCH 2
#define T 2048
#define E 1024
#define NH 16
#define HD 64
#define M (BATCH*T)   // 4096
#define K3 (3*E)      // 3072
#define VOCAB 32000

typedef __attribute__((ext_vector_type(8))) short s16x8;
typedef __attribute__((ext_vector_type(4))) short s16x4;
typedef __attribute__((ext_vector_type(4))) float f32x4;

__device__ inline unsigned short f2bf(float f) {
  union { float f; unsigned u; } x; x.f = f;
  unsigned r = x.u + 0x7fffu + ((x.u >> 16) & 1u);   // RNE
  return (unsigned short)(r >> 16);
}

__device__ inline void gload16(const void* g, void* l) {
  __builtin_amdgcn_global_load_lds(
      (const __attribute__((address_space(1))) unsigned int*)g,
      (__attribute__((address_space(3))) unsigned int*)l, 16, 0, 0);
}

// ---- weight transpose+convert body: W[1024][N] f32 -> Wt[N][1024] bf16 ----
__device__ inline void wt_body(const float* __restrict__ W,
    unsigned short* __restrict__ Wt, int N, int n0, int k0, int t,
    float (*tile)[65]) {
  int kl = t >> 2, c = t & 3;
  #pragma unroll
  for (int i = 0; i < 4; i++) {
    float4 v4 = *(const float4*)(W + (size_t)(k0 + kl) * N + n0 + c * 16 + i * 4);
    tile[kl][c * 16 + i * 4 + 0] = v4.x;
    tile[kl][c * 16 + i * 4 + 1] = v4.y;
    tile[kl][c * 16 + i * 4 + 2] = v4.z;
    tile[kl][c * 16 + i * 4 + 3] = v4.w;
  }
  __syncthreads();
  #pragma unroll
  for (int j = 0; j < 2; j++) {
    int idx = t + j * 256;
    int nl = idx >> 3, kq = (idx & 7) * 8;
    s16x8 o;
    #pragma unroll
    for (int i = 0; i < 8; i++) o[i] = (short)f2bf(tile[kq + i][nl]);
    *(s16x8*)(Wt + (size_t)(n0 + nl) * 1024 + k0 + kq) = o;
  }
}

// ---------------- k_pre: embed + wt(qkv_w) + wt(proj_w) fused ----------------
__global__ __launch_bounds__(256) void k_pre(const int* __restrict__ x,
    const float* __restrict__ tok, const float* __restrict__ pos,
    unsigned short* __restrict__ hb,
    const float* __restrict__ qkvw, unsigned short* __restrict__ qkvwt,
    const float* __restrict__ projw, unsigned short* __restrict__ projwt) {
  __shared__ __align__(16) float tile[64][65];
  int gid = blockIdx.x, t = threadIdx.x;
  if (gid < 4096) {
    int row = gid;
    int tt = row & (T - 1);
    int tokid = x[row];
    float4 a = ((const float4*)(tok + (size_t)tokid * E))[t];
    float4 p = ((const float4*)(pos + (size_t)tt * E))[t];
    s16x4 o;
    o[0] = (short)f2bf(a.x + p.x); o[1] = (short)f2bf(a.y + p.y);
    o[2] = (short)f2bf(a.z + p.z); o[3] = (short)f2bf(a.w + p.w);
    *(s16x4*)(hb + (size_t)row * E + t * 4) = o;
    return;
  }
  if (gid < 4864) {
    int idx = gid - 4096;
    wt_body(qkvw, qkvwt, K3, (idx % 48) * 64, (idx / 48) * 64, t, tile);
    return;
  }
  int idx = gid - 4864;
  wt_body(projw, projwt, E, (idx % 16) * 64, (idx / 16) * 64, t, tile);
}

// ---------------- bf16 MFMA GEMM 128x128 (m97 structure) ----------------
// MODE 0: fp32 C + bias.  MODE 2: bf16 C + bias.  (used for proj + fallback)
template<int MODE>
__global__ __launch_bounds__(256) void k_bgemm(
    const unsigned short* __restrict__ A, const unsigned short* __restrict__ Bt,
    const float* __restrict__ bias, float* __restrict__ C, int N,
    unsigned short* __restrict__ Cb) {
  __shared__ char lds[16384];
  char* As = lds;
  char* Bs = lds + 8192;
  int tid = threadIdx.x;
  int lane = tid & 63;
  int wv = tid >> 6;
  int wm = wv >> 1, wn = wv & 1;
  int n0 = blockIdx.x * 128, m0 = blockIdx.y * 128;
  int fr = lane & 15, fq = lane >> 4;

  f32x4 acc[4][4];
  #pragma unroll
  for (int i = 0; i < 4; i++)
    #pragma unroll
    for (int j = 0; j < 4; j++) acc[i][j] = (f32x4){0.f, 0.f, 0.f, 0.f};

  int p0 = tid * 16, p1 = tid * 16 + 4096;
  int r0 = p0 >> 6, c0 = p0 & 63;
  int r1 = p1 >> 6, c1 = p1 & 63;
  int cs0 = c0 ^ (((r0 >> 1) & 3) << 4);
  int cs1 = c1 ^ (((r1 >> 1) & 3) << 4);
  const char* ga0 = (const char*)(A + (size_t)(m0 + r0) * 1024) + cs0;
  const char* ga1 = (const char*)(A + (size_t)(m0 + r1) * 1024) + cs1;
  const char* gb0 = (const char*)(Bt + (size_t)(n0 + r0) * 1024) + cs0;
  const char* gb1 = (const char*)(Bt + (size_t)(n0 + r1) * 1024) + cs1;

  int aoff[4], boff[4];
  #pragma unroll
  for (int i = 0; i < 4; i++) {
    int ra = wm * 64 + i * 16 + fr;
    aoff[i] = ra * 64 + ((fq * 16) ^ (((ra >> 1) & 3) << 4));
    int rb = wn * 64 + i * 16 + fr;
    boff[i] = rb * 64 + ((fq * 16) ^ (((rb >> 1) & 3) << 4));
  }

  for (int kb = 0; kb < 2048; kb += 64) {
    gload16(ga0 + kb, As + p0);
    gload16(ga1 + kb, As + p1);
    gload16(gb0 + kb, Bs + p0);
    gload16(gb1 + kb, Bs + p1);
    __syncthreads();
    s16x8 af[4], bfr[4];
    #pragma unroll
    for (int i = 0; i < 4; i++) af[i] = *(const s16x8*)(As + aoff[i]);
    #pragma unroll
    for (int i = 0; i < 4; i++) bfr[i] = *(const s16x8*)(Bs + boff[i]);
    #pragma unroll
    for (int mi = 0; mi < 4; mi++)
      #pragma unroll
      for (int ni = 0; ni < 4; ni++)
        acc[mi][ni] = __builtin_amdgcn_mfma_f32_16x16x32_bf16(
            af[mi], bfr[ni], acc[mi][ni], 0, 0, 0);
    __syncthreads();
  }

  #pragma unroll
  for (int mi = 0; mi < 4; mi++) {
    #pragma unroll
    for (int ni = 0; ni < 4; ni++) {
      #pragma unroll
      for (int j = 0; j < 4; j++) {
        int m = m0 + wm * 64 + mi * 16 + fq * 4 + j;
        int n = n0 + wn * 64 + ni * 16 + fr;
        float val = acc[mi][ni][j] + bias[n];
        if (MODE == 0) C[(size_t)m * N + n] = val;
        else           Cb[(size_t)m * 1024 + n] = f2bf(val);
      }
    }
  }
}

// ---------------- qkv GEMM: R4-256² structure + scatter epilogue ----------------
__global__ __launch_bounds__(512, 2) void k_qkv(
    const unsigned short* __restrict__ A, const unsigned short* __restrict__ Bt,
    const float* __restrict__ bias,
    unsigned short* __restrict__ qo, unsigned short* __restrict__ ko,
    unsigned short* __restrict__ vo) {
  __shared__ __align__(16) char lds[131072];
  int tid = threadIdx.x, lane = tid & 63, wv = tid >> 6;
  int WM = wv >> 2, WN = wv & 3;
  int fr = lane & 15, fq = lane >> 4;

  int bid = blockIdx.x;                 // 192 blocks
  int wg = (bid & 7) * 24 + (bid >> 3); // bijective (192 % 8 == 0)
  int m0 = (wg % 16) * 256;
  int n0 = (wg / 16) * 256;

  const char* gA[4]; const char* gB[4]; int lo[4];
  #pragma unroll
  for (int j = 0; j < 4; j++) {
    int i = tid + j * 512;
    int r = i >> 3, c = i & 7;
    int cc = c ^ (r & 7);
    gA[j] = (const char*)A + ((size_t)(m0 + r) * 1024 + cc * 8) * 2;
    gB[j] = (const char*)Bt + ((size_t)(n0 + r) * 1024 + cc * 8) * 2;
    lo[j] = i * 16;
  }

  f32x4 acc[8][4];
  #pragma unroll
  for (int i = 0; i < 8; i++)
    #pragma unroll
    for (int j = 0; j < 4; j++) acc[i][j] = (f32x4){0.f, 0.f, 0.f, 0.f};

  #pragma unroll
  for (int j = 0; j < 4; j++) {
    gload16(gA[j], lds + lo[j]);
    gload16(gB[j], lds + 65536 + lo[j]);
  }
  __syncthreads();

  for (int t = 0; t < 16; t++) {
    int cur = t & 1;
    if (t + 1 < 16) {
      int kb = (t + 1) * 128;
      int nxt = cur ^ 1;
      #pragma unroll
      for (int j = 0; j < 4; j++) {
        gload16(gA[j] + kb, lds + nxt * 32768 + lo[j]);
        gload16(gB[j] + kb, lds + 65536 + nxt * 32768 + lo[j]);
      }
    }
    const char* As = lds + cur * 32768;
    const char* Bs = lds + 65536 + cur * 32768;
    #pragma unroll
    for (int kh = 0; kh < 2; kh++) {
      s16x8 af[8], bf[4];
      #pragma unroll
      for (int mi = 0; mi < 8; mi++) {
        int r = WM * 128 + mi * 16 + fr;
        af[mi] = *(const s16x8*)(As + r * 128 + (((kh * 4 + fq) ^ (r & 7)) << 4));
      }
      #pragma unroll
      for (int ni = 0; ni < 4; ni++) {
        int r = WN * 64 + ni * 16 + fr;
        bf[ni] = *(const s16x8*)(Bs + r * 128 + (((kh * 4 + fq) ^ (r & 7)) << 4));
      }
      __builtin_amdgcn_s_setprio(1);
      #pragma unroll
      for (int mi = 0; mi < 8; mi++)
        #pragma unroll
        for (int ni = 0; ni < 4; ni++)
          acc[mi][ni] = __builtin_amdgcn_mfma_f32_16x16x32_bf16(
              af[mi], bf[ni], acc[mi][ni], 0, 0, 0);
      __builtin_amdgcn_s_setprio(0);
    }
    __syncthreads();
  }

  #pragma unroll
  for (int mi = 0; mi < 8; mi++) {
    #pragma unroll
    for (int ni = 0; ni < 4; ni++) {
      int n = n0 + WN * 64 + ni * 16 + fr;
      int which = n >> 10;
      int e = n & (E - 1);
      int hh = e >> 6, d = e & 63;
      int mb = m0 + WM * 128 + mi * 16 + fq * 4;
      int b = mb >> 11, tt0 = mb & (T - 1);
      float bv = bias[n];
      if (which == 2) {
        s16x4 pk;
        #pragma unroll
        for (int j = 0; j < 4; j++) pk[j] = (short)f2bf(acc[mi][ni][j] + bv);
        *(s16x4*)(vo + ((size_t)(b * NH + hh) * 64 + d) * T + tt0) = pk;
      } else {
        unsigned short* dst = (which == 0) ? qo : ko;
        #pragma unroll
        for (int j = 0; j < 4; j++)
          dst[((size_t)(b * NH + hh) * T + tt0 + j) * 64 + d] =
              f2bf(acc[mi][ni][j] + bv);
      }
    }
  }
}

// ---------------- fc GEMM: R4-exact 16x16x32 (x4 reproduced at 321-327 us) ----------------
// R17 lesson: 32x32 fragments are a STRUCTURAL 4-way LDS conflict in row-major
// 128B-row tiles (bank = f(chunk only); 32 rows share 8 chunk slots) — no
// chunk-XOR fixes it. 16x16 (16 rows/chunk-set -> 2-way = free, m136) stays.
__global__ __launch_bounds__(512, 2) void k_fc(
    const unsigned short* __restrict__ A, const unsigned short* __restrict__ Bt,
    const float* __restrict__ bias, float* __restrict__ C) {
  __shared__ __align__(16) char lds[131072];  // As0|As1 @0,32K ; Bs0|Bs1 @64K,96K
  int tid = threadIdx.x, lane = tid & 63, wv = tid >> 6;
  int WM = wv >> 2, WN = wv & 3;              // 2M x 4N waves, per-wave 128x64
  int fr = lane & 15, fq = lane >> 4;

  int bid = blockIdx.x;
  int wg = (bid & 7) * 250 + (bid >> 3);
  int m0 = (wg & 15) * 256;
  int n0 = (wg >> 4) * 256;

  const char* gA[4]; const char* gB[4]; int lo[4];
  #pragma unroll
  for (int j = 0; j < 4; j++) {
    int i = tid + j * 512;
    int r = i >> 3, c = i & 7;
    int cc = c ^ (r & 7);
    gA[j] = (const char*)A + ((size_t)(m0 + r) * 1024 + cc * 8) * 2;
    gB[j] = (const char*)Bt + ((size_t)(n0 + r) * 1024 + cc * 8) * 2;
    lo[j] = i * 16;
  }

  f32x4 acc[8][4];
  #pragma unroll
  for (int i = 0; i < 8; i++)
    #pragma unroll
    for (int j = 0; j < 4; j++) acc[i][j] = (f32x4){0.f, 0.f, 0.f, 0.f};

  #pragma unroll
  for (int j = 0; j < 4; j++) {
    gload16(gA[j], lds + lo[j]);
    gload16(gB[j], lds + 65536 + lo[j]);
  }
  __syncthreads();

  for (int t = 0; t < 16; t++) {
    int cur = t & 1;
    if (t + 1 < 16) {
      int kb = (t + 1) * 128;
      int nxt = cur ^ 1;
      #pragma unroll
      for (int j = 0; j < 4; j++) {
        gload16(gA[j] + kb, lds + nxt * 32768 + lo[j]);
        gload16(gB[j] + kb, lds + 65536 + nxt * 32768 + lo[j]);
      }
    }
    const char* As = lds + cur * 32768;
    const char* Bs = lds + 65536 + cur * 32768;
    #pragma unroll
    for (int kh = 0; kh < 2; kh++) {
      s16x8 af[8], bf[4];
      #pragma unroll
      for (int mi = 0; mi < 8; mi++) {
        int r = WM * 128 + mi * 16 + fr;
        af[mi] = *(const s16x8*)(As + r * 128 + (((kh * 4 + fq) ^ (r & 7)) << 4));
      }
      #pragma unroll
      for (int ni = 0; ni < 4; ni++) {
        int r = WN * 64 + ni * 16 + fr;
        bf[ni] = *(const s16x8*)(Bs + r * 128 + (((kh * 4 + fq) ^ (r & 7)) << 4));
      }
      __builtin_amdgcn_s_setprio(1);
      #pragma unroll
      for (int mi = 0; mi < 8; mi++)
        #pragma unroll
        for (int ni = 0; ni < 4; ni++)
          acc[mi][ni] = __builtin_amdgcn_mfma_f32_16x16x32_bf16(
              af[mi], bf[ni], acc[mi][ni], 0, 0, 0);
      __builtin_amdgcn_s_setprio(0);
    }
    __syncthreads();
  }

  #pragma unroll
  for (int mi = 0; mi < 8; mi++) {
    #pragma unroll
    for (int ni = 0; ni < 4; ni++) {
      int n = n0 + WN * 64 + ni * 16 + fr;
      float bv = bias[n];
      #pragma unroll
      for (int j = 0; j < 4; j++) {
        int m = m0 + WM * 128 + mi * 16 + fq * 4 + j;
        C[(size_t)m * VOCAB + n] = acc[mi][ni][j] + bv;
      }
    }
  }
}

// ---------------- fp32 GEMM fallback (small-ws path only) ----------------
#define BM 128
#define BN 128
#define BKF 32
#define LDT (BM + 4)
__global__ __launch_bounds__(256) void k_gemm32(
    const float* __restrict__ A, const float* __restrict__ Bw,
    const float* __restrict__ bias, float* __restrict__ C, int N) {
  __shared__ float As[BKF * LDT];
  __shared__ float Bs[BKF * LDT];
  int tid = threadIdx.x;
  int tx = tid & 15, ty = tid >> 4;
  int n0 = blockIdx.x * BN;
  int m0 = blockIdx.y * BM;
  float acc[8][8];
  #pragma unroll
  for (int i = 0; i < 8; i++)
    #pragma unroll
    for (int j = 0; j < 8; j++) acc[i][j] = 0.f;
  for (int k0 = 0; k0 < E; k0 += BKF) {
    #pragma unroll
    for (int i = 0; i < 4; i++) {
      int f = i * 256 + tid;
      int ml = f >> 3, c4 = f & 7;
      float4 va = *(const float4*)(A + (size_t)(m0 + ml) * E + k0 + c4 * 4);
      As[(c4 * 4 + 0) * LDT + ml] = va.x;
      As[(c4 * 4 + 1) * LDT + ml] = va.y;
      As[(c4 * 4 + 2) * LDT + ml] = va.z;
      As[(c4 * 4 + 3) * LDT + ml] = va.w;
    }
    #pragma unroll
    for (int i = 0; i < 4; i++) {
      int f = i * 256 + tid;
      int kk = f >> 5, c4 = f & 31;
      float4 vb = *(const float4*)(Bw + (size_t)(k0 + kk) * N + n0 + c4 * 4);
      *(float4*)(Bs + kk * LDT + c4 * 4) = vb;
    }
    __syncthreads();
    #pragma unroll
    for (int kk = 0; kk < BKF; kk++) {
      const float4* ar = (const float4*)(As + kk * LDT);
      const float4* br = (const float4*)(Bs + kk * LDT);
      float4 a0 = ar[ty * 2], a1 = ar[ty * 2 + 1];
      float4 b0 = br[tx * 2], b1 = br[tx * 2 + 1];
      float av[8] = {a0.x, a0.y, a0.z, a0.w, a1.x, a1.y, a1.z, a1.w};
      float bvv[8] = {b0.x, b0.y, b0.z, b0.w, b1.x, b1.y, b1.z, b1.w};
      #pragma unroll
      for (int i = 0; i < 8; i++)
        #pragma unroll
        for (int j = 0; j < 8; j++)
          acc[i][j] = fmaf(av[i], bvv[j], acc[i][j]);
    }
    __syncthreads();
  }
  int mbase = m0 + ty * 8;
  int nbase = n0 + tx * 8;
  #pragma unroll
  for (int i = 0; i < 8; i++) {
    float* crow = C + (size_t)(mbase + i) * N + nbase;
    #pragma unroll
    for (int j = 0; j < 8; j++) crow[j] = acc[i][j] + bias[nbase + j];
  }
}

// ---------------- fused: MFMA flash attention + wt(fc_w) ----------------
// attn: QBLK=128, shared K/V fragments across q-row groups, ballot-gated
// defer-max (R17-proven tail win). blocks 512+: fc weight transpose.
__global__ __launch_bounds__(256) void k_attn_wt(
    const unsigned short* __restrict__ qb, const unsigned short* __restrict__ kb,
    const unsigned short* __restrict__ vtb, unsigned short* __restrict__ o,
    const float* __restrict__ fcw, unsigned short* __restrict__ fcwt) {
  __shared__ __align__(16) char lds[49152];  // K dbuf 16K | Vt dbuf 16K | P 4x4K
  int gid = blockIdx.x;
  int tid = threadIdx.x;

  if (gid >= 512) {
    int idx = gid - 512;
    wt_body(fcw, fcwt, VOCAB, (idx % 500) * 64, (idx / 500) * 64, tid,
            (float(*)[65])lds);
    return;
  }

  int qt = 15 - (gid >> 5);
  int bh = gid & 31;
  int b = bh >> 4, hh = bh & 15;
  int lane = tid & 63, wv = tid >> 6;
  int fr = lane & 15, fq = lane >> 4;
  int q0 = qt * 128;
  int qw0 = q0 + wv * 32;
  const char* Kg = (const char*)(kb + (size_t)bh * T * 64);
  const char* Vg = (const char*)(vtb + (size_t)bh * 64 * T);
  char* Pl = lds + 32768 + wv * 4096;

  s16x8 qf[2][2];
  #pragma unroll
  for (int g = 0; g < 2; g++) {
    const unsigned short* Qg = qb + ((size_t)bh * T + qw0 + g * 16) * 64;
    qf[g][0] = *(const s16x8*)(Qg + (size_t)fr * 64 + fq * 8);
    qf[g][1] = *(const s16x8*)(Qg + (size_t)fr * 64 + 32 + fq * 8);
  }

  f32x4 po[2][4];
  float mrow[2][4], lrow[2][4];
  #pragma unroll
  for (int g = 0; g < 2; g++)
    #pragma unroll
    for (int j = 0; j < 4; j++) {
      po[g][j] = (f32x4){0.f, 0.f, 0.f, 0.f};
      mrow[g][j] = -1e30f; lrow[g][j] = 0.f;
    }

  int ntiles = qt * 2 + 2;
  int i0 = tid, i1 = tid + 256;
  int sr0 = i0 >> 3, sc0 = ((i0 & 7) ^ (sr0 & 7)) << 4;
  int sr1 = i1 >> 3, sc1 = ((i1 & 7) ^ (sr1 & 7)) << 4;

  {
    gload16(Kg + (size_t)sr0 * 128 + sc0, lds + i0 * 16);
    gload16(Kg + (size_t)sr1 * 128 + sc1, lds + i1 * 16);
    gload16(Vg + (size_t)sr0 * (T * 2) + sc0, lds + 16384 + i0 * 16);
    gload16(Vg + (size_t)sr1 * (T * 2) + sc1, lds + 16384 + i1 * 16);
  }
  __syncthreads();
  int cur = 0;

  for (int kt = 0; kt < ntiles; kt++) {
    int kv0 = kt * 64;
    if (kt + 1 < ntiles) {
      size_t kvn = (size_t)(kv0 + 64);
      char* kd = lds + (cur ^ 1) * 8192;
      char* vd = lds + 16384 + (cur ^ 1) * 8192;
      gload16(Kg + (kvn + sr0) * 128 + sc0, kd + i0 * 16);
      gload16(Kg + (kvn + sr1) * 128 + sc1, kd + i1 * 16);
      gload16(Vg + (size_t)sr0 * (T * 2) + kvn * 2 + sc0, vd + i0 * 16);
      gload16(Vg + (size_t)sr1 * (T * 2) + kvn * 2 + sc1, vd + i1 * 16);
    }
    const char* Kt = lds + cur * 8192;
    const char* Vt = lds + 16384 + cur * 8192;

    f32x4 s[2][4];
    #pragma unroll
    for (int ni = 0; ni < 4; ni++) {
      int r = ni * 16 + fr;
      s16x8 kf0 = *(const s16x8*)(Kt + r * 128 + ((fq ^ (r & 7)) << 4));
      s16x8 kf1 = *(const s16x8*)(Kt + r * 128 + (((4 + fq) ^ (r & 7)) << 4));
      #pragma unroll
      for (int g = 0; g < 2; g++) {
        s[g][ni] = (f32x4){0.f, 0.f, 0.f, 0.f};
        s[g][ni] = __builtin_amdgcn_mfma_f32_16x16x32_bf16(qf[g][0], kf0, s[g][ni], 0, 0, 0);
        s[g][ni] = __builtin_amdgcn_mfma_f32_16x16x32_bf16(qf[g][1], kf1, s[g][ni], 0, 0, 0);
      }
    }

    #pragma unroll
    for (int g = 0; g < 2; g++) {
      int qw = qw0 + g * 16;
      bool needm = (kv0 + 63 > qw);
      #pragma unroll
      for (int jj = 0; jj < 4; jj++) {
        int row = qw + fq * 4 + jj;
        float tm = -1e30f;
        #pragma unroll
        for (int ni = 0; ni < 4; ni++) {
          float val = s[g][ni][jj] * 0.125f;
          if (needm) { int col = kv0 + ni * 16 + fr; if (col > row) val = -1e30f; }
          s[g][ni][jj] = val;
          tm = fmaxf(tm, val);
        }
        if (__any(tm > mrow[g][jj] + 8.f)) {
          float twm = tm;
          #pragma unroll
          for (int mk = 1; mk < 16; mk <<= 1) twm = fmaxf(twm, __shfl_xor(twm, mk));
          float nm = fmaxf(mrow[g][jj], twm);
          float corr = __expf(mrow[g][jj] - nm);
          mrow[g][jj] = nm;
          #pragma unroll
          for (int ni = 0; ni < 4; ni++) po[g][ni][jj] *= corr;
          lrow[g][jj] *= corr;
        }
        float mref = mrow[g][jj];
        float rs = 0.f;
        #pragma unroll
        for (int ni = 0; ni < 4; ni++) {
          float pv = __expf(s[g][ni][jj] - mref);
          s[g][ni][jj] = pv;
          rs += pv;
        }
        #pragma unroll
        for (int mk = 1; mk < 16; mk <<= 1) rs += __shfl_xor(rs, mk);
        lrow[g][jj] += rs;
      }
    }

    asm volatile("s_waitcnt lgkmcnt(0)" ::: "memory");
    #pragma unroll
    for (int g = 0; g < 2; g++) {
      char* Pg = Pl + g * 2048;
      #pragma unroll
      for (int ni = 0; ni < 4; ni++) {
        int col = ni * 16 + fr;
        #pragma unroll
        for (int jj = 0; jj < 4; jj++) {
          int qq = fq * 4 + jj;
          *(unsigned short*)(Pg + qq * 128 + (((col >> 3) ^ (qq & 7)) << 4) +
                             (col & 7) * 2) = f2bf(s[g][ni][jj]);
        }
      }
    }
    asm volatile("s_waitcnt lgkmcnt(0)" ::: "memory");

    s16x8 pa[2][2];
    #pragma unroll
    for (int g = 0; g < 2; g++) {
      const char* Pg = Pl + g * 2048;
      pa[g][0] = *(const s16x8*)(Pg + fr * 128 + ((fq ^ (fr & 7)) << 4));
      pa[g][1] = *(const s16x8*)(Pg + fr * 128 + (((4 + fq) ^ (fr & 7)) << 4));
    }
    #pragma unroll
    for (int ni = 0; ni < 4; ni++) {
      int r = ni * 16 + fr;
      s16x8 vf0 = *(const s16x8*)(Vt + r * 128 + ((fq ^ (r & 7)) << 4));
      s16x8 vf1 = *(const s16x8*)(Vt + r * 128 + (((4 + fq) ^ (r & 7)) << 4));
      #pragma unroll
      for (int g = 0; g < 2; g++) {
        po[g][ni] = __builtin_amdgcn_mfma_f32_16x16x32_bf16(pa[g][0], vf0, po[g][ni], 0, 0, 0);
        po[g][ni] = __builtin_amdgcn_mfma_f32_16x16x32_bf16(pa[g][1], vf1, po[g][ni], 0, 0, 0);
      }
    }
    __syncthreads();
    cur ^= 1;
  }

  #pragma unroll
  for (int g = 0; g < 2; g++)
    #pragma unroll
    for (int jj = 0; jj < 4; jj++) {
      float inv = 1.f / lrow[g][jj];
      int row = qw0 + g * 16 + fq * 4 + jj;
      unsigned short* orow = o + ((size_t)(b * T + row)) * E + hh * 64;
      #pragma unroll
      for (int ni = 0; ni < 4; ni++)
        orow[ni * 16 + fr] = f2bf(po[g][ni][jj] * inv);
    }
}

extern "C" void kernel_launch(void* const* d_in, const int* in_sizes, int n_in,
                              void* d_out, int out_size, void* d_ws, size_t ws_size,
                              hipStream_t stream) {
  const int*   x      = (const int*)d_in[0];
  const float* tok    = (const float*)d_in[1];
  const float* pos    = (const float*)d_in[2];
  const float* qkv_w  = (const float*)d_in[3];
  const float* qkv_b  = (const float*)d_in[4];
  const float* proj_w = (const float*)d_in[5];
  const float* proj_b = (const float*)d_in[6];
  const float* fc_w   = (const float*)d_in[7];
  const float* fc_b   = (const float*)d_in[8];
  float* out = (float*)d_out;
  float* ws  = (float*)d_ws;

  // scratch layout in d_out (fully overwritten by fc at the end)
  unsigned short* hb      = (unsigned short*)out;                     // 2,097,152 f
  unsigned short* qkv_wt  = (unsigned short*)(out + 2097152);         // 1,572,864 f
  unsigned short* qbuf    = (unsigned short*)(out + 3670016);         // 2,097,152 f
  unsigned short* kbuf    = (unsigned short*)(out + 5767168);         // 2,097,152 f
  unsigned short* vtbuf   = (unsigned short*)(out + 7864320);         // 2,097,152 f
  unsigned short* aob     = (unsigned short*)(out + 9961472);         // 2,097,152 f
  unsigned short* proj_wt = (unsigned short*)(out + 12058624);        //   524,288 f

  const size_t WS_FAST = (size_t)(2097152 + 16384000) * 4;

  k_pre<<<5120, 256, 0, stream>>>(x, tok, pos, hb, qkv_w, qkv_wt, proj_w, proj_wt);
  k_qkv<<<192, 512, 0, stream>>>(hb, qkv_wt, qkv_b, qbuf, kbuf, vtbuf);

  if (ws_size >= WS_FAST) {
    unsigned short* h2b   = (unsigned short*)ws;
    unsigned short* fc_wt = (unsigned short*)(ws + 2097152);
    k_attn_wt<<<8512, 256, 0, stream>>>(qbuf, kbuf, vtbuf, aob, fc_w, fc_wt);
    k_bgemm<2><<<dim3(E / 128, M / 128), 256, 0, stream>>>(
        aob, proj_wt, proj_b, nullptr, E, h2b);
    k_fc<<<dim3((M / 256) * (VOCAB / 256)), 512, 0, stream>>>(
        h2b, fc_wt, fc_b, out);
  } else {
    float* h2 = ws;
    k_attn_wt<<<512, 256, 0, stream>>>(qbuf, kbuf, vtbuf, aob, nullptr, nullptr);
    k_bgemm<0><<<dim3(E / 128, M / 128), 256, 0, stream>>>(
        aob, proj_wt, proj_b, h2, E, nullptr);
    k_gemm32<<<dim3(VOCAB / BN, M / BM), 256, 0, stream>>>(
        h2, fc_w, fc_b, out, VOCAB);
  }
}

// Round 20
// 473.056 us; speedup vs baseline: 1.0428x; 1.0064x over previous
//
#include <hip/hip_runtime.h>

#define BATCH 2
#define T 2048
#define E 1024
#define NH 16
#define HD 64
#define M (BATCH*T)   // 4096
#define K3 (3*E)      // 3072
#define VOCAB 32000

typedef __attribute__((ext_vector_type(8))) short s16x8;
typedef __attribute__((ext_vector_type(4))) short s16x4;
typedef __attribute__((ext_vector_type(4))) float f32x4;

__device__ inline unsigned short f2bf(float f) {
  union { float f; unsigned u; } x; x.f = f;
  unsigned r = x.u + 0x7fffu + ((x.u >> 16) & 1u);   // RNE
  return (unsigned short)(r >> 16);
}

__device__ inline void gload16(const void* g, void* l) {
  __builtin_amdgcn_global_load_lds(
      (const __attribute__((address_space(1))) unsigned int*)g,
      (__attribute__((address_space(3))) unsigned int*)l, 16, 0, 0);
}

// ---- weight transpose+convert body: W[1024][N] f32 -> Wt[N][1024] bf16 ----
__device__ inline void wt_body(const float* __restrict__ W,
    unsigned short* __restrict__ Wt, int N, int n0, int k0, int t,
    float (*tile)[65]) {
  int kl = t >> 2, c = t & 3;
  #pragma unroll
  for (int i = 0; i < 4; i++) {
    float4 v4 = *(const float4*)(W + (size_t)(k0 + kl) * N + n0 + c * 16 + i * 4);
    tile[kl][c * 16 + i * 4 + 0] = v4.x;
    tile[kl][c * 16 + i * 4 + 1] = v4.y;
    tile[kl][c * 16 + i * 4 + 2] = v4.z;
    tile[kl][c * 16 + i * 4 + 3] = v4.w;
  }
  __syncthreads();
  #pragma unroll
  for (int j = 0; j < 2; j++) {
    int idx = t + j * 256;
    int nl = idx >> 3, kq = (idx & 7) * 8;
    s16x8 o;
    #pragma unroll
    for (int i = 0; i < 8; i++) o[i] = (short)f2bf(tile[kq + i][nl]);
    *(s16x8*)(Wt + (size_t)(n0 + nl) * 1024 + k0 + kq) = o;
  }
}

// ---------------- k_pre: embed + wt(qkv_w) + wt(proj_w) fused ----------------
__global__ __launch_bounds__(256) void k_pre(const int* __restrict__ x,
    const float* __restrict__ tok, const float* __restrict__ pos,
    unsigned short* __restrict__ hb,
    const float* __restrict__ qkvw, unsigned short* __restrict__ qkvwt,
    const float* __restrict__ projw, unsigned short* __restrict__ projwt) {
  __shared__ __align__(16) float tile[64][65];
  int gid = blockIdx.x, t = threadIdx.x;
  if (gid < 4096) {
    int row = gid;
    int tt = row & (T - 1);
    int tokid = x[row];
    float4 a = ((const float4*)(tok + (size_t)tokid * E))[t];
    float4 p = ((const float4*)(pos + (size_t)tt * E))[t];
    s16x4 o;
    o[0] = (short)f2bf(a.x + p.x); o[1] = (short)f2bf(a.y + p.y);
    o[2] = (short)f2bf(a.z + p.z); o[3] = (short)f2bf(a.w + p.w);
    *(s16x4*)(hb + (size_t)row * E + t * 4) = o;
    return;
  }
  if (gid < 4864) {
    int idx = gid - 4096;
    wt_body(qkvw, qkvwt, K3, (idx % 48) * 64, (idx / 48) * 64, t, tile);
    return;
  }
  int idx = gid - 4864;
  wt_body(projw, projwt, E, (idx % 16) * 64, (idx / 16) * 64, t, tile);
}

// ---------------- bf16 MFMA GEMM 128x128 (m97 structure) ----------------
// MODE 0: fp32 C + bias.  MODE 2: bf16 C + bias.  (used for proj + fallback)
template<int MODE>
__global__ __launch_bounds__(256) void k_bgemm(
    const unsigned short* __restrict__ A, const unsigned short* __restrict__ Bt,
    const float* __restrict__ bias, float* __restrict__ C, int N,
    unsigned short* __restrict__ Cb) {
  __shared__ char lds[16384];
  char* As = lds;
  char* Bs = lds + 8192;
  int tid = threadIdx.x;
  int lane = tid & 63;
  int wv = tid >> 6;
  int wm = wv >> 1, wn = wv & 1;
  int n0 = blockIdx.x * 128, m0 = blockIdx.y * 128;
  int fr = lane & 15, fq = lane >> 4;

  f32x4 acc[4][4];
  #pragma unroll
  for (int i = 0; i < 4; i++)
    #pragma unroll
    for (int j = 0; j < 4; j++) acc[i][j] = (f32x4){0.f, 0.f, 0.f, 0.f};

  int p0 = tid * 16, p1 = tid * 16 + 4096;
  int r0 = p0 >> 6, c0 = p0 & 63;
  int r1 = p1 >> 6, c1 = p1 & 63;
  int cs0 = c0 ^ (((r0 >> 1) & 3) << 4);
  int cs1 = c1 ^ (((r1 >> 1) & 3) << 4);
  const char* ga0 = (const char*)(A + (size_t)(m0 + r0) * 1024) + cs0;
  const char* ga1 = (const char*)(A + (size_t)(m0 + r1) * 1024) + cs1;
  const char* gb0 = (const char*)(Bt + (size_t)(n0 + r0) * 1024) + cs0;
  const char* gb1 = (const char*)(Bt + (size_t)(n0 + r1) * 1024) + cs1;

  int aoff[4], boff[4];
  #pragma unroll
  for (int i = 0; i < 4; i++) {
    int ra = wm * 64 + i * 16 + fr;
    aoff[i] = ra * 64 + ((fq * 16) ^ (((ra >> 1) & 3) << 4));
    int rb = wn * 64 + i * 16 + fr;
    boff[i] = rb * 64 + ((fq * 16) ^ (((rb >> 1) & 3) << 4));
  }

  for (int kb = 0; kb < 2048; kb += 64) {
    gload16(ga0 + kb, As + p0);
    gload16(ga1 + kb, As + p1);
    gload16(gb0 + kb, Bs + p0);
    gload16(gb1 + kb, Bs + p1);
    __syncthreads();
    s16x8 af[4], bfr[4];
    #pragma unroll
    for (int i = 0; i < 4; i++) af[i] = *(const s16x8*)(As + aoff[i]);
    #pragma unroll
    for (int i = 0; i < 4; i++) bfr[i] = *(const s16x8*)(Bs + boff[i]);
    #pragma unroll
    for (int mi = 0; mi < 4; mi++)
      #pragma unroll
      for (int ni = 0; ni < 4; ni++)
        acc[mi][ni] = __builtin_amdgcn_mfma_f32_16x16x32_bf16(
            af[mi], bfr[ni], acc[mi][ni], 0, 0, 0);
    __syncthreads();
  }

  #pragma unroll
  for (int mi = 0; mi < 4; mi++) {
    #pragma unroll
    for (int ni = 0; ni < 4; ni++) {
      #pragma unroll
      for (int j = 0; j < 4; j++) {
        int m = m0 + wm * 64 + mi * 16 + fq * 4 + j;
        int n = n0 + wn * 64 + ni * 16 + fr;
        float val = acc[mi][ni][j] + bias[n];
        if (MODE == 0) C[(size_t)m * N + n] = val;
        else           Cb[(size_t)m * 1024 + n] = f2bf(val);
      }
    }
  }
}

// ---------------- qkv GEMM: R4-256² structure + scatter epilogue ----------------
__global__ __launch_bounds__(512, 2) void k_qkv(
    const unsigned short* __restrict__ A, const unsigned short* __restrict__ Bt,
    const float* __restrict__ bias,
    unsigned short* __restrict__ qo, unsigned short* __restrict__ ko,
    unsigned short* __restrict__ vo) {
  __shared__ __align__(16) char lds[131072];
  int tid = threadIdx.x, lane = tid & 63, wv = tid >> 6;
  int WM = wv >> 2, WN = wv & 3;
  int fr = lane & 15, fq = lane >> 4;

  int bid = blockIdx.x;                 // 192 blocks
  int wg = (bid & 7) * 24 + (bid >> 3); // bijective (192 % 8 == 0)
  int m0 = (wg % 16) * 256;
  int n0 = (wg / 16) * 256;

  const char* gA[4]; const char* gB[4]; int lo[4];
  #pragma unroll
  for (int j = 0; j < 4; j++) {
    int i = tid + j * 512;
    int r = i >> 3, c = i & 7;
    int cc = c ^ (r & 7);
    gA[j] = (const char*)A + ((size_t)(m0 + r) * 1024 + cc * 8) * 2;
    gB[j] = (const char*)Bt + ((size_t)(n0 + r) * 1024 + cc * 8) * 2;
    lo[j] = i * 16;
  }

  f32x4 acc[8][4];
  #pragma unroll
  for (int i = 0; i < 8; i++)
    #pragma unroll
    for (int j = 0; j < 4; j++) acc[i][j] = (f32x4){0.f, 0.f, 0.f, 0.f};

  #pragma unroll
  for (int j = 0; j < 4; j++) {
    gload16(gA[j], lds + lo[j]);
    gload16(gB[j], lds + 65536 + lo[j]);
  }
  __syncthreads();

  for (int t = 0; t < 16; t++) {
    int cur = t & 1;
    if (t + 1 < 16) {
      int kb = (t + 1) * 128;
      int nxt = cur ^ 1;
      #pragma unroll
      for (int j = 0; j < 4; j++) {
        gload16(gA[j] + kb, lds + nxt * 32768 + lo[j]);
        gload16(gB[j] + kb, lds + 65536 + nxt * 32768 + lo[j]);
      }
    }
    const char* As = lds + cur * 32768;
    const char* Bs = lds + 65536 + cur * 32768;
    #pragma unroll
    for (int kh = 0; kh < 2; kh++) {
      s16x8 af[8], bf[4];
      #pragma unroll
      for (int mi = 0; mi < 8; mi++) {
        int r = WM * 128 + mi * 16 + fr;
        af[mi] = *(const s16x8*)(As + r * 128 + (((kh * 4 + fq) ^ (r & 7)) << 4));
      }
      #pragma unroll
      for (int ni = 0; ni < 4; ni++) {
        int r = WN * 64 + ni * 16 + fr;
        bf[ni] = *(const s16x8*)(Bs + r * 128 + (((kh * 4 + fq) ^ (r & 7)) << 4));
      }
      __builtin_amdgcn_s_setprio(1);
      #pragma unroll
      for (int mi = 0; mi < 8; mi++)
        #pragma unroll
        for (int ni = 0; ni < 4; ni++)
          acc[mi][ni] = __builtin_amdgcn_mfma_f32_16x16x32_bf16(
              af[mi], bf[ni], acc[mi][ni], 0, 0, 0);
      __builtin_amdgcn_s_setprio(0);
    }
    __syncthreads();
  }

  #pragma unroll
  for (int mi = 0; mi < 8; mi++) {
    #pragma unroll
    for (int ni = 0; ni < 4; ni++) {
      int n = n0 + WN * 64 + ni * 16 + fr;
      int which = n >> 10;
      int e = n & (E - 1);
      int hh = e >> 6, d = e & 63;
      int mb = m0 + WM * 128 + mi * 16 + fq * 4;
      int b = mb >> 11, tt0 = mb & (T - 1);
      float bv = bias[n];
      if (which == 2) {
        s16x4 pk;
        #pragma unroll
        for (int j = 0; j < 4; j++) pk[j] = (short)f2bf(acc[mi][ni][j] + bv);
        *(s16x4*)(vo + ((size_t)(b * NH + hh) * 64 + d) * T + tt0) = pk;
      } else {
        unsigned short* dst = (which == 0) ? qo : ko;
        #pragma unroll
        for (int j = 0; j < 4; j++)
          dst[((size_t)(b * NH + hh) * T + tt0 + j) * 64 + d] =
              f2bf(acc[mi][ni][j] + bv);
      }
    }
  }
}

// ---------------- fc GEMM: R4-exact 16x16x32 (x4 reproduced at 321-327 us) ----------------
// R17 lesson: 32x32 fragments are a STRUCTURAL 4-way LDS conflict in row-major
// 128B-row tiles (bank = f(chunk only); 32 rows share 8 chunk slots) — no
// chunk-XOR fixes it. 16x16 (16 rows/chunk-set -> 2-way = free, m136) stays.
__global__ __launch_bounds__(512, 2) void k_fc(
    const unsigned short* __restrict__ A, const unsigned short* __restrict__ Bt,
    const float* __restrict__ bias, float* __restrict__ C) {
  __shared__ __align__(16) char lds[131072];  // As0|As1 @0,32K ; Bs0|Bs1 @64K,96K
  int tid = threadIdx.x, lane = tid & 63, wv = tid >> 6;
  int WM = wv >> 2, WN = wv & 3;              // 2M x 4N waves, per-wave 128x64
  int fr = lane & 15, fq = lane >> 4;

  int bid = blockIdx.x;
  int wg = (bid & 7) * 250 + (bid >> 3);
  int m0 = (wg & 15) * 256;
  int n0 = (wg >> 4) * 256;

  const char* gA[4]; const char* gB[4]; int lo[4];
  #pragma unroll
  for (int j = 0; j < 4; j++) {
    int i = tid + j * 512;
    int r = i >> 3, c = i & 7;
    int cc = c ^ (r & 7);
    gA[j] = (const char*)A + ((size_t)(m0 + r) * 1024 + cc * 8) * 2;
    gB[j] = (const char*)Bt + ((size_t)(n0 + r) * 1024 + cc * 8) * 2;
    lo[j] = i * 16;
  }

  f32x4 acc[8][4];
  #pragma unroll
  for (int i = 0; i < 8; i++)
    #pragma unroll
    for (int j = 0; j < 4; j++) acc[i][j] = (f32x4){0.f, 0.f, 0.f, 0.f};

  #pragma unroll
  for (int j = 0; j < 4; j++) {
    gload16(gA[j], lds + lo[j]);
    gload16(gB[j], lds + 65536 + lo[j]);
  }
  __syncthreads();

  for (int t = 0; t < 16; t++) {
    int cur = t & 1;
    if (t + 1 < 16) {
      int kb = (t + 1) * 128;
      int nxt = cur ^ 1;
      #pragma unroll
      for (int j = 0; j < 4; j++) {
        gload16(gA[j] + kb, lds + nxt * 32768 + lo[j]);
        gload16(gB[j] + kb, lds + 65536 + nxt * 32768 + lo[j]);
      }
    }
    const char* As = lds + cur * 32768;
    const char* Bs = lds + 65536 + cur * 32768;
    #pragma unroll
    for (int kh = 0; kh < 2; kh++) {
      s16x8 af[8], bf[4];
      #pragma unroll
      for (int mi = 0; mi < 8; mi++) {
        int r = WM * 128 + mi * 16 + fr;
        af[mi] = *(const s16x8*)(As + r * 128 + (((kh * 4 + fq) ^ (r & 7)) << 4));
      }
      #pragma unroll
      for (int ni = 0; ni < 4; ni++) {
        int r = WN * 64 + ni * 16 + fr;
        bf[ni] = *(const s16x8*)(Bs + r * 128 + (((kh * 4 + fq) ^ (r & 7)) << 4));
      }
      __builtin_amdgcn_s_setprio(1);
      #pragma unroll
      for (int mi = 0; mi < 8; mi++)
        #pragma unroll
        for (int ni = 0; ni < 4; ni++)
          acc[mi][ni] = __builtin_amdgcn_mfma_f32_16x16x32_bf16(
              af[mi], bf[ni], acc[mi][ni], 0, 0, 0);
      __builtin_amdgcn_s_setprio(0);
    }
    __syncthreads();
  }

  #pragma unroll
  for (int mi = 0; mi < 8; mi++) {
    #pragma unroll
    for (int ni = 0; ni < 4; ni++) {
      int n = n0 + WN * 64 + ni * 16 + fr;
      float bv = bias[n];
      #pragma unroll
      for (int j = 0; j < 4; j++) {
        int m = m0 + WM * 128 + mi * 16 + fq * 4 + j;
        C[(size_t)m * VOCAB + n] = acc[mi][ni][j] + bv;
      }
    }
  }
}

// ---------------- fp32 GEMM fallback (small-ws path only) ----------------
#define BM 128
#define BN 128
#define BKF 32
#define LDT (BM + 4)
__global__ __launch_bounds__(256) void k_gemm32(
    const float* __restrict__ A, const float* __restrict__ Bw,
    const float* __restrict__ bias, float* __restrict__ C, int N) {
  __shared__ float As[BKF * LDT];
  __shared__ float Bs[BKF * LDT];
  int tid = threadIdx.x;
  int tx = tid & 15, ty = tid >> 4;
  int n0 = blockIdx.x * BN;
  int m0 = blockIdx.y * BM;
  float acc[8][8];
  #pragma unroll
  for (int i = 0; i < 8; i++)
    #pragma unroll
    for (int j = 0; j < 8; j++) acc[i][j] = 0.f;
  for (int k0 = 0; k0 < E; k0 += BKF) {
    #pragma unroll
    for (int i = 0; i < 4; i++) {
      int f = i * 256 + tid;
      int ml = f >> 3, c4 = f & 7;
      float4 va = *(const float4*)(A + (size_t)(m0 + ml) * E + k0 + c4 * 4);
      As[(c4 * 4 + 0) * LDT + ml] = va.x;
      As[(c4 * 4 + 1) * LDT + ml] = va.y;
      As[(c4 * 4 + 2) * LDT + ml] = va.z;
      As[(c4 * 4 + 3) * LDT + ml] = va.w;
    }
    #pragma unroll
    for (int i = 0; i < 4; i++) {
      int f = i * 256 + tid;
      int kk = f >> 5, c4 = f & 31;
      float4 vb = *(const float4*)(Bw + (size_t)(k0 + kk) * N + n0 + c4 * 4);
      *(float4*)(Bs + kk * LDT + c4 * 4) = vb;
    }
    __syncthreads();
    #pragma unroll
    for (int kk = 0; kk < BKF; kk++) {
      const float4* ar = (const float4*)(As + kk * LDT);
      const float4* br = (const float4*)(Bs + kk * LDT);
      float4 a0 = ar[ty * 2], a1 = ar[ty * 2 + 1];
      float4 b0 = br[tx * 2], b1 = br[tx * 2 + 1];
      float av[8] = {a0.x, a0.y, a0.z, a0.w, a1.x, a1.y, a1.z, a1.w};
      float bvv[8] = {b0.x, b0.y, b0.z, b0.w, b1.x, b1.y, b1.z, b1.w};
      #pragma unroll
      for (int i = 0; i < 8; i++)
        #pragma unroll
        for (int j = 0; j < 8; j++)
          acc[i][j] = fmaf(av[i], bvv[j], acc[i][j]);
    }
    __syncthreads();
  }
  int mbase = m0 + ty * 8;
  int nbase = n0 + tx * 8;
  #pragma unroll
  for (int i = 0; i < 8; i++) {
    float* crow = C + (size_t)(mbase + i) * N + nbase;
    #pragma unroll
    for (int j = 0; j < 8; j++) crow[j] = acc[i][j] + bias[nbase + j];
  }
}

// ---------------- fused: MFMA flash attention + wt(fc_w) ----------------
// attn: QBLK=128, shared K/V fragments across q-row groups, ballot-gated
// defer-max (R17-proven tail win). blocks 512+: fc weight transpose.
__global__ __launch_bounds__(256) void k_attn_wt(
    const unsigned short* __restrict__ qb, const unsigned short* __restrict__ kb,
    const unsigned short* __restrict__ vtb, unsigned short* __restrict__ o,
    const float* __restrict__ fcw, unsigned short* __restrict__ fcwt) {
  __shared__ __align__(16) char lds[49152];  // K dbuf 16K | Vt dbuf 16K | P 4x4K
  int gid = blockIdx.x;
  int tid = threadIdx.x;

  if (gid >= 512) {
    int idx = gid - 512;
    wt_body(fcw, fcwt, VOCAB, (idx % 500) * 64, (idx / 500) * 64, tid,
            (float(*)[65])lds);
    return;
  }

  int qt = 15 - (gid >> 5);
  int bh = gid & 31;
  int b = bh >> 4, hh = bh & 15;
  int lane = tid & 63, wv = tid >> 6;
  int fr = lane & 15, fq = lane >> 4;
  int q0 = qt * 128;
  int qw0 = q0 + wv * 32;
  const char* Kg = (const char*)(kb + (size_t)bh * T * 64);
  const char* Vg = (const char*)(vtb + (size_t)bh * 64 * T);
  char* Pl = lds + 32768 + wv * 4096;

  s16x8 qf[2][2];
  #pragma unroll
  for (int g = 0; g < 2; g++) {
    const unsigned short* Qg = qb + ((size_t)bh * T + qw0 + g * 16) * 64;
    qf[g][0] = *(const s16x8*)(Qg + (size_t)fr * 64 + fq * 8);
    qf[g][1] = *(const s16x8*)(Qg + (size_t)fr * 64 + 32 + fq * 8);
  }

  f32x4 po[2][4];
  float mrow[2][4], lrow[2][4];
  #pragma unroll
  for (int g = 0; g < 2; g++)
    #pragma unroll
    for (int j = 0; j < 4; j++) {
      po[g][j] = (f32x4){0.f, 0.f, 0.f, 0.f};
      mrow[g][j] = -1e30f; lrow[g][j] = 0.f;
    }

  int ntiles = qt * 2 + 2;
  int i0 = tid, i1 = tid + 256;
  int sr0 = i0 >> 3, sc0 = ((i0 & 7) ^ (sr0 & 7)) << 4;
  int sr1 = i1 >> 3, sc1 = ((i1 & 7) ^ (sr1 & 7)) << 4;

  {
    gload16(Kg + (size_t)sr0 * 128 + sc0, lds + i0 * 16);
    gload16(Kg + (size_t)sr1 * 128 + sc1, lds + i1 * 16);
    gload16(Vg + (size_t)sr0 * (T * 2) + sc0, lds + 16384 + i0 * 16);
    gload16(Vg + (size_t)sr1 * (T * 2) + sc1, lds + 16384 + i1 * 16);
  }
  __syncthreads();
  int cur = 0;

  for (int kt = 0; kt < ntiles; kt++) {
    int kv0 = kt * 64;
    if (kt + 1 < ntiles) {
      size_t kvn = (size_t)(kv0 + 64);
      char* kd = lds + (cur ^ 1) * 8192;
      char* vd = lds + 16384 + (cur ^ 1) * 8192;
      gload16(Kg + (kvn + sr0) * 128 + sc0, kd + i0 * 16);
      gload16(Kg + (kvn + sr1) * 128 + sc1, kd + i1 * 16);
      gload16(Vg + (size_t)sr0 * (T * 2) + kvn * 2 + sc0, vd + i0 * 16);
      gload16(Vg + (size_t)sr1 * (T * 2) + kvn * 2 + sc1, vd + i1 * 16);
    }
    const char* Kt = lds + cur * 8192;
    const char* Vt = lds + 16384 + cur * 8192;

    f32x4 s[2][4];
    #pragma unroll
    for (int ni = 0; ni < 4; ni++) {
      int r = ni * 16 + fr;
      s16x8 kf0 = *(const s16x8*)(Kt + r * 128 + ((fq ^ (r & 7)) << 4));
      s16x8 kf1 = *(const s16x8*)(Kt + r * 128 + (((4 + fq) ^ (r & 7)) << 4));
      #pragma unroll
      for (int g = 0; g < 2; g++) {
        s[g][ni] = (f32x4){0.f, 0.f, 0.f, 0.f};
        s[g][ni] = __builtin_amdgcn_mfma_f32_16x16x32_bf16(qf[g][0], kf0, s[g][ni], 0, 0, 0);
        s[g][ni] = __builtin_amdgcn_mfma_f32_16x16x32_bf16(qf[g][1], kf1, s[g][ni], 0, 0, 0);
      }
    }

    #pragma unroll
    for (int g = 0; g < 2; g++) {
      int qw = qw0 + g * 16;
      bool needm = (kv0 + 63 > qw);
      #pragma unroll
      for (int jj = 0; jj < 4; jj++) {
        int row = qw + fq * 4 + jj;
        float tm = -1e30f;
        #pragma unroll
        for (int ni = 0; ni < 4; ni++) {
          float val = s[g][ni][jj] * 0.125f;
          if (needm) { int col = kv0 + ni * 16 + fr; if (col > row) val = -1e30f; }
          s[g][ni][jj] = val;
          tm = fmaxf(tm, val);
        }
        if (__any(tm > mrow[g][jj] + 8.f)) {
          float twm = tm;
          #pragma unroll
          for (int mk = 1; mk < 16; mk <<= 1) twm = fmaxf(twm, __shfl_xor(twm, mk));
          float nm = fmaxf(mrow[g][jj], twm);
          float corr = __expf(mrow[g][jj] - nm);
          mrow[g][jj] = nm;
          #pragma unroll
          for (int ni = 0; ni < 4; ni++) po[g][ni][jj] *= corr;
          lrow[g][jj] *= corr;
        }
        float mref = mrow[g][jj];
        float rs = 0.f;
        #pragma unroll
        for (int ni = 0; ni < 4; ni++) {
          float pv = __expf(s[g][ni][jj] - mref);
          s[g][ni][jj] = pv;
          rs += pv;
        }
        #pragma unroll
        for (int mk = 1; mk < 16; mk <<= 1) rs += __shfl_xor(rs, mk);
        lrow[g][jj] += rs;
      }
    }

    asm volatile("s_waitcnt lgkmcnt(0)" ::: "memory");
    #pragma unroll
    for (int g = 0; g < 2; g++) {
      char* Pg = Pl + g * 2048;
      #pragma unroll
      for (int ni = 0; ni < 4; ni++) {
        int col = ni * 16 + fr;
        #pragma unroll
        for (int jj = 0; jj < 4; jj++) {
          int qq = fq * 4 + jj;
          *(unsigned short*)(Pg + qq * 128 + (((col >> 3) ^ (qq & 7)) << 4) +
                             (col & 7) * 2) = f2bf(s[g][ni][jj]);
        }
      }
    }
    asm volatile("s_waitcnt lgkmcnt(0)" ::: "memory");

    s16x8 pa[2][2];
    #pragma unroll
    for (int g = 0; g < 2; g++) {
      const char* Pg = Pl + g * 2048;
      pa[g][0] = *(const s16x8*)(Pg + fr * 128 + ((fq ^ (fr & 7)) << 4));
      pa[g][1] = *(const s16x8*)(Pg + fr * 128 + (((4 + fq) ^ (fr & 7)) << 4));
    }
    #pragma unroll
    for (int ni = 0; ni < 4; ni++) {
      int r = ni * 16 + fr;
      s16x8 vf0 = *(const s16x8*)(Vt + r * 128 + ((fq ^ (r & 7)) << 4));
      s16x8 vf1 = *(const s16x8*)(Vt + r * 128 + (((4 + fq) ^ (r & 7)) << 4));
      #pragma unroll
      for (int g = 0; g < 2; g++) {
        po[g][ni] = __builtin_amdgcn_mfma_f32_16x16x32_bf16(pa[g][0], vf0, po[g][ni], 0, 0, 0);
        po[g][ni] = __builtin_amdgcn_mfma_f32_16x16x32_bf16(pa[g][1], vf1, po[g][ni], 0, 0, 0);
      }
    }
    __syncthreads();
    cur ^= 1;
  }

  #pragma unroll
  for (int g = 0; g < 2; g++)
    #pragma unroll
    for (int jj = 0; jj < 4; jj++) {
      float inv = 1.f / lrow[g][jj];
      int row = qw0 + g * 16 + fq * 4 + jj;
      unsigned short* orow = o + ((size_t)(b * T + row)) * E + hh * 64;
      #pragma unroll
      for (int ni = 0; ni < 4; ni++)
        orow[ni * 16 + fr] = f2bf(po[g][ni][jj] * inv);
    }
}

extern "C" void kernel_launch(void* const* d_in, const int* in_sizes, int n_in,
                              void* d_out, int out_size, void* d_ws, size_t ws_size,
                              hipStream_t stream) {
  const int*   x      = (const int*)d_in[0];
  const float* tok    = (const float*)d_in[1];
  const float* pos    = (const float*)d_in[2];
  const float* qkv_w  = (const float*)d_in[3];
  const float* qkv_b  = (const float*)d_in[4];
  const float* proj_w = (const float*)d_in[5];
  const float* proj_b = (const float*)d_in[6];
  const float* fc_w   = (const float*)d_in[7];
  const float* fc_b   = (const float*)d_in[8];
  float* out = (float*)d_out;
  float* ws  = (float*)d_ws;

  // scratch layout in d_out (fully overwritten by fc at the end)
  unsigned short* hb      = (unsigned short*)out;                     // 2,097,152 f
  unsigned short* qkv_wt  = (unsigned short*)(out + 2097152);         // 1,572,864 f
  unsigned short* qbuf    = (unsigned short*)(out + 3670016);         // 2,097,152 f
  unsigned short* kbuf    = (unsigned short*)(out + 5767168);         // 2,097,152 f
  unsigned short* vtbuf   = (unsigned short*)(out + 7864320);         // 2,097,152 f
  unsigned short* aob     = (unsigned short*)(out + 9961472);         // 2,097,152 f
  unsigned short* proj_wt = (unsigned short*)(out + 12058624);        //   524,288 f

  const size_t WS_FAST = (size_t)(2097152 + 16384000) * 4;

  k_pre<<<5120, 256, 0, stream>>>(x, tok, pos, hb, qkv_w, qkv_wt, proj_w, proj_wt);
  k_qkv<<<192, 512, 0, stream>>>(hb, qkv_wt, qkv_b, qbuf, kbuf, vtbuf);

  if (ws_size >= WS_FAST) {
    unsigned short* h2b   = (unsigned short*)ws;
    unsigned short* fc_wt = (unsigned short*)(ws + 2097152);
    k_attn_wt<<<8512, 256, 0, stream>>>(qbuf, kbuf, vtbuf, aob, fc_w, fc_wt);
    k_bgemm<2><<<dim3(E / 128, M / 128), 256, 0, stream>>>(
        aob, proj_wt, proj_b, nullptr, E, h2b);
    k_fc<<<dim3((M / 256) * (VOCAB / 256)), 512, 0, stream>>>(
        h2b, fc_wt, fc_b, out);
  } else {
    float* h2 = ws;
    k_attn_wt<<<512, 256, 0, stream>>>(qbuf, kbuf, vtbuf, aob, nullptr, nullptr);
    k_bgemm<0><<<dim3(E / 128, M / 128), 256, 0, stream>>>(
        aob, proj_wt, proj_b, h2, E, nullptr);
    k_gemm32<<<dim3(VOCAB / BN, M / BM), 256, 0, stream>>>(
        h2, fc_w, fc_b, out, VOCAB);
  }
}

// Round 21
// 469.374 us; speedup vs baseline: 1.0510x; 1.0078x over previous
//
#include <hip/hip_runtime.h>

#define BATCH 2
#define T 2048
#define E 1024
#define NH 16
#define HD 64
#define M (BATCH*T)   // 4096
#define K3 (3*E)      // 3072
#define VOCAB 32000

typedef __attribute__((ext_vector_type(8))) short s16x8;
typedef __attribute__((ext_vector_type(4))) short s16x4;
typedef __attribute__((ext_vector_type(4))) float f32x4;

__device__ inline unsigned short f2bf(float f) {
  union { float f; unsigned u; } x; x.f = f;
  unsigned r = x.u + 0x7fffu + ((x.u >> 16) & 1u);   // RNE
  return (unsigned short)(r >> 16);
}

__device__ inline void gload16(const void* g, void* l) {
  __builtin_amdgcn_global_load_lds(
      (const __attribute__((address_space(1))) unsigned int*)g,
      (__attribute__((address_space(3))) unsigned int*)l, 16, 0, 0);
}

// ---- weight transpose+convert body: W[1024][N] f32 -> Wt[N][1024] bf16 ----
__device__ inline void wt_body(const float* __restrict__ W,
    unsigned short* __restrict__ Wt, int N, int n0, int k0, int t,
    float (*tile)[65]) {
  int kl = t >> 2, c = t & 3;
  #pragma unroll
  for (int i = 0; i < 4; i++) {
    float4 v4 = *(const float4*)(W + (size_t)(k0 + kl) * N + n0 + c * 16 + i * 4);
    tile[kl][c * 16 + i * 4 + 0] = v4.x;
    tile[kl][c * 16 + i * 4 + 1] = v4.y;
    tile[kl][c * 16 + i * 4 + 2] = v4.z;
    tile[kl][c * 16 + i * 4 + 3] = v4.w;
  }
  __syncthreads();
  #pragma unroll
  for (int j = 0; j < 2; j++) {
    int idx = t + j * 256;
    int nl = idx >> 3, kq = (idx & 7) * 8;
    s16x8 o;
    #pragma unroll
    for (int i = 0; i < 8; i++) o[i] = (short)f2bf(tile[kq + i][nl]);
    *(s16x8*)(Wt + (size_t)(n0 + nl) * 1024 + k0 + kq) = o;
  }
}

// ---------------- k_pre: embed + wt(qkv_w) + wt(proj_w) fused ----------------
__global__ __launch_bounds__(256) void k_pre(const int* __restrict__ x,
    const float* __restrict__ tok, const float* __restrict__ pos,
    unsigned short* __restrict__ hb,
    const float* __restrict__ qkvw, unsigned short* __restrict__ qkvwt,
    const float* __restrict__ projw, unsigned short* __restrict__ projwt) {
  __shared__ __align__(16) float tile[64][65];
  int gid = blockIdx.x, t = threadIdx.x;
  if (gid < 4096) {
    int row = gid;
    int tt = row & (T - 1);
    int tokid = x[row];
    float4 a = ((const float4*)(tok + (size_t)tokid * E))[t];
    float4 p = ((const float4*)(pos + (size_t)tt * E))[t];
    s16x4 o;
    o[0] = (short)f2bf(a.x + p.x); o[1] = (short)f2bf(a.y + p.y);
    o[2] = (short)f2bf(a.z + p.z); o[3] = (short)f2bf(a.w + p.w);
    *(s16x4*)(hb + (size_t)row * E + t * 4) = o;
    return;
  }
  if (gid < 4864) {
    int idx = gid - 4096;
    wt_body(qkvw, qkvwt, K3, (idx % 48) * 64, (idx / 48) * 64, t, tile);
    return;
  }
  int idx = gid - 4864;
  wt_body(projw, projwt, E, (idx % 16) * 64, (idx / 16) * 64, t, tile);
}

// ---------------- bf16 MFMA GEMM 128x128 (m97 structure) ----------------
// MODE 0: fp32 C + bias.  MODE 2: bf16 C + bias.  (used for proj + fallback)
template<int MODE>
__global__ __launch_bounds__(256) void k_bgemm(
    const unsigned short* __restrict__ A, const unsigned short* __restrict__ Bt,
    const float* __restrict__ bias, float* __restrict__ C, int N,
    unsigned short* __restrict__ Cb) {
  __shared__ char lds[16384];
  char* As = lds;
  char* Bs = lds + 8192;
  int tid = threadIdx.x;
  int lane = tid & 63;
  int wv = tid >> 6;
  int wm = wv >> 1, wn = wv & 1;
  int n0 = blockIdx.x * 128, m0 = blockIdx.y * 128;
  int fr = lane & 15, fq = lane >> 4;

  f32x4 acc[4][4];
  #pragma unroll
  for (int i = 0; i < 4; i++)
    #pragma unroll
    for (int j = 0; j < 4; j++) acc[i][j] = (f32x4){0.f, 0.f, 0.f, 0.f};

  int p0 = tid * 16, p1 = tid * 16 + 4096;
  int r0 = p0 >> 6, c0 = p0 & 63;
  int r1 = p1 >> 6, c1 = p1 & 63;
  int cs0 = c0 ^ (((r0 >> 1) & 3) << 4);
  int cs1 = c1 ^ (((r1 >> 1) & 3) << 4);
  const char* ga0 = (const char*)(A + (size_t)(m0 + r0) * 1024) + cs0;
  const char* ga1 = (const char*)(A + (size_t)(m0 + r1) * 1024) + cs1;
  const char* gb0 = (const char*)(Bt + (size_t)(n0 + r0) * 1024) + cs0;
  const char* gb1 = (const char*)(Bt + (size_t)(n0 + r1) * 1024) + cs1;

  int aoff[4], boff[4];
  #pragma unroll
  for (int i = 0; i < 4; i++) {
    int ra = wm * 64 + i * 16 + fr;
    aoff[i] = ra * 64 + ((fq * 16) ^ (((ra >> 1) & 3) << 4));
    int rb = wn * 64 + i * 16 + fr;
    boff[i] = rb * 64 + ((fq * 16) ^ (((rb >> 1) & 3) << 4));
  }

  for (int kb = 0; kb < 2048; kb += 64) {
    gload16(ga0 + kb, As + p0);
    gload16(ga1 + kb, As + p1);
    gload16(gb0 + kb, Bs + p0);
    gload16(gb1 + kb, Bs + p1);
    __syncthreads();
    s16x8 af[4], bfr[4];
    #pragma unroll
    for (int i = 0; i < 4; i++) af[i] = *(const s16x8*)(As + aoff[i]);
    #pragma unroll
    for (int i = 0; i < 4; i++) bfr[i] = *(const s16x8*)(Bs + boff[i]);
    #pragma unroll
    for (int mi = 0; mi < 4; mi++)
      #pragma unroll
      for (int ni = 0; ni < 4; ni++)
        acc[mi][ni] = __builtin_amdgcn_mfma_f32_16x16x32_bf16(
            af[mi], bfr[ni], acc[mi][ni], 0, 0, 0);
    __syncthreads();
  }

  #pragma unroll
  for (int mi = 0; mi < 4; mi++) {
    #pragma unroll
    for (int ni = 0; ni < 4; ni++) {
      #pragma unroll
      for (int j = 0; j < 4; j++) {
        int m = m0 + wm * 64 + mi * 16 + fq * 4 + j;
        int n = n0 + wn * 64 + ni * 16 + fr;
        float val = acc[mi][ni][j] + bias[n];
        if (MODE == 0) C[(size_t)m * N + n] = val;
        else           Cb[(size_t)m * 1024 + n] = f2bf(val);
      }
    }
  }
}

// ---------------- qkv GEMM: R4-256² structure + scatter epilogue ----------------
__global__ __launch_bounds__(512, 2) void k_qkv(
    const unsigned short* __restrict__ A, const unsigned short* __restrict__ Bt,
    const float* __restrict__ bias,
    unsigned short* __restrict__ qo, unsigned short* __restrict__ ko,
    unsigned short* __restrict__ vo) {
  __shared__ __align__(16) char lds[131072];
  int tid = threadIdx.x, lane = tid & 63, wv = tid >> 6;
  int WM = wv >> 2, WN = wv & 3;
  int fr = lane & 15, fq = lane >> 4;

  int bid = blockIdx.x;                 // 192 blocks
  int wg = (bid & 7) * 24 + (bid >> 3); // bijective (192 % 8 == 0)
  int m0 = (wg % 16) * 256;
  int n0 = (wg / 16) * 256;

  const char* gA[4]; const char* gB[4]; int lo[4];
  #pragma unroll
  for (int j = 0; j < 4; j++) {
    int i = tid + j * 512;
    int r = i >> 3, c = i & 7;
    int cc = c ^ (r & 7);
    gA[j] = (const char*)A + ((size_t)(m0 + r) * 1024 + cc * 8) * 2;
    gB[j] = (const char*)Bt + ((size_t)(n0 + r) * 1024 + cc * 8) * 2;
    lo[j] = i * 16;
  }

  f32x4 acc[8][4];
  #pragma unroll
  for (int i = 0; i < 8; i++)
    #pragma unroll
    for (int j = 0; j < 4; j++) acc[i][j] = (f32x4){0.f, 0.f, 0.f, 0.f};

  #pragma unroll
  for (int j = 0; j < 4; j++) {
    gload16(gA[j], lds + lo[j]);
    gload16(gB[j], lds + 65536 + lo[j]);
  }
  __syncthreads();

  for (int t = 0; t < 16; t++) {
    int cur = t & 1;
    if (t + 1 < 16) {
      int kb = (t + 1) * 128;
      int nxt = cur ^ 1;
      #pragma unroll
      for (int j = 0; j < 4; j++) {
        gload16(gA[j] + kb, lds + nxt * 32768 + lo[j]);
        gload16(gB[j] + kb, lds + 65536 + nxt * 32768 + lo[j]);
      }
    }
    const char* As = lds + cur * 32768;
    const char* Bs = lds + 65536 + cur * 32768;
    #pragma unroll
    for (int kh = 0; kh < 2; kh++) {
      s16x8 af[8], bf[4];
      #pragma unroll
      for (int mi = 0; mi < 8; mi++) {
        int r = WM * 128 + mi * 16 + fr;
        af[mi] = *(const s16x8*)(As + r * 128 + (((kh * 4 + fq) ^ (r & 7)) << 4));
      }
      #pragma unroll
      for (int ni = 0; ni < 4; ni++) {
        int r = WN * 64 + ni * 16 + fr;
        bf[ni] = *(const s16x8*)(Bs + r * 128 + (((kh * 4 + fq) ^ (r & 7)) << 4));
      }
      __builtin_amdgcn_s_setprio(1);
      #pragma unroll
      for (int mi = 0; mi < 8; mi++)
        #pragma unroll
        for (int ni = 0; ni < 4; ni++)
          acc[mi][ni] = __builtin_amdgcn_mfma_f32_16x16x32_bf16(
              af[mi], bf[ni], acc[mi][ni], 0, 0, 0);
      __builtin_amdgcn_s_setprio(0);
    }
    __syncthreads();
  }

  #pragma unroll
  for (int mi = 0; mi < 8; mi++) {
    #pragma unroll
    for (int ni = 0; ni < 4; ni++) {
      int n = n0 + WN * 64 + ni * 16 + fr;
      int which = n >> 10;
      int e = n & (E - 1);
      int hh = e >> 6, d = e & 63;
      int mb = m0 + WM * 128 + mi * 16 + fq * 4;
      int b = mb >> 11, tt0 = mb & (T - 1);
      float bv = bias[n];
      if (which == 2) {
        s16x4 pk;
        #pragma unroll
        for (int j = 0; j < 4; j++) pk[j] = (short)f2bf(acc[mi][ni][j] + bv);
        *(s16x4*)(vo + ((size_t)(b * NH + hh) * 64 + d) * T + tt0) = pk;
      } else {
        unsigned short* dst = (which == 0) ? qo : ko;
        #pragma unroll
        for (int j = 0; j < 4; j++)
          dst[((size_t)(b * NH + hh) * T + tt0 + j) * 64 + d] =
              f2bf(acc[mi][ni][j] + bv);
      }
    }
  }
}

// ---------------- fc GEMM: R4-exact + NON-TEMPORAL C stores ----------------
// R20 counter anomaly: FETCH 342MB vs 74MB unique inputs — the 523MB fp32
// C-stream evicts B-panels from L2/L3 (output never re-read). Fix: nt stores
// keep C out of the cache hierarchy, preserving A/B residency. Semantics
// identical (cache hint only).
__global__ __launch_bounds__(512, 2) void k_fc(
    const unsigned short* __restrict__ A, const unsigned short* __restrict__ Bt,
    const float* __restrict__ bias, float* __restrict__ C) {
  __shared__ __align__(16) char lds[131072];  // As0|As1 @0,32K ; Bs0|Bs1 @64K,96K
  int tid = threadIdx.x, lane = tid & 63, wv = tid >> 6;
  int WM = wv >> 2, WN = wv & 3;              // 2M x 4N waves, per-wave 128x64
  int fr = lane & 15, fq = lane >> 4;

  int bid = blockIdx.x;
  int wg = (bid & 7) * 250 + (bid >> 3);
  int m0 = (wg & 15) * 256;
  int n0 = (wg >> 4) * 256;

  const char* gA[4]; const char* gB[4]; int lo[4];
  #pragma unroll
  for (int j = 0; j < 4; j++) {
    int i = tid + j * 512;
    int r = i >> 3, c = i & 7;
    int cc = c ^ (r & 7);
    gA[j] = (const char*)A + ((size_t)(m0 + r) * 1024 + cc * 8) * 2;
    gB[j] = (const char*)Bt + ((size_t)(n0 + r) * 1024 + cc * 8) * 2;
    lo[j] = i * 16;
  }

  f32x4 acc[8][4];
  #pragma unroll
  for (int i = 0; i < 8; i++)
    #pragma unroll
    for (int j = 0; j < 4; j++) acc[i][j] = (f32x4){0.f, 0.f, 0.f, 0.f};

  #pragma unroll
  for (int j = 0; j < 4; j++) {
    gload16(gA[j], lds + lo[j]);
    gload16(gB[j], lds + 65536 + lo[j]);
  }
  __syncthreads();

  for (int t = 0; t < 16; t++) {
    int cur = t & 1;
    if (t + 1 < 16) {
      int kb = (t + 1) * 128;
      int nxt = cur ^ 1;
      #pragma unroll
      for (int j = 0; j < 4; j++) {
        gload16(gA[j] + kb, lds + nxt * 32768 + lo[j]);
        gload16(gB[j] + kb, lds + 65536 + nxt * 32768 + lo[j]);
      }
    }
    const char* As = lds + cur * 32768;
    const char* Bs = lds + 65536 + cur * 32768;
    #pragma unroll
    for (int kh = 0; kh < 2; kh++) {
      s16x8 af[8], bf[4];
      #pragma unroll
      for (int mi = 0; mi < 8; mi++) {
        int r = WM * 128 + mi * 16 + fr;
        af[mi] = *(const s16x8*)(As + r * 128 + (((kh * 4 + fq) ^ (r & 7)) << 4));
      }
      #pragma unroll
      for (int ni = 0; ni < 4; ni++) {
        int r = WN * 64 + ni * 16 + fr;
        bf[ni] = *(const s16x8*)(Bs + r * 128 + (((kh * 4 + fq) ^ (r & 7)) << 4));
      }
      __builtin_amdgcn_s_setprio(1);
      #pragma unroll
      for (int mi = 0; mi < 8; mi++)
        #pragma unroll
        for (int ni = 0; ni < 4; ni++)
          acc[mi][ni] = __builtin_amdgcn_mfma_f32_16x16x32_bf16(
              af[mi], bf[ni], acc[mi][ni], 0, 0, 0);
      __builtin_amdgcn_s_setprio(0);
    }
    __syncthreads();
  }

  // epilogue: fp32 + bias, non-temporal (C never re-read)
  #pragma unroll
  for (int mi = 0; mi < 8; mi++) {
    #pragma unroll
    for (int ni = 0; ni < 4; ni++) {
      int n = n0 + WN * 64 + ni * 16 + fr;
      float bv = bias[n];
      #pragma unroll
      for (int j = 0; j < 4; j++) {
        int m = m0 + WM * 128 + mi * 16 + fq * 4 + j;
        __builtin_nontemporal_store(acc[mi][ni][j] + bv, &C[(size_t)m * VOCAB + n]);
      }
    }
  }
}

// ---------------- fp32 GEMM fallback (small-ws path only) ----------------
#define BM 128
#define BN 128
#define BKF 32
#define LDT (BM + 4)
__global__ __launch_bounds__(256) void k_gemm32(
    const float* __restrict__ A, const float* __restrict__ Bw,
    const float* __restrict__ bias, float* __restrict__ C, int N) {
  __shared__ float As[BKF * LDT];
  __shared__ float Bs[BKF * LDT];
  int tid = threadIdx.x;
  int tx = tid & 15, ty = tid >> 4;
  int n0 = blockIdx.x * BN;
  int m0 = blockIdx.y * BM;
  float acc[8][8];
  #pragma unroll
  for (int i = 0; i < 8; i++)
    #pragma unroll
    for (int j = 0; j < 8; j++) acc[i][j] = 0.f;
  for (int k0 = 0; k0 < E; k0 += BKF) {
    #pragma unroll
    for (int i = 0; i < 4; i++) {
      int f = i * 256 + tid;
      int ml = f >> 3, c4 = f & 7;
      float4 va = *(const float4*)(A + (size_t)(m0 + ml) * E + k0 + c4 * 4);
      As[(c4 * 4 + 0) * LDT + ml] = va.x;
      As[(c4 * 4 + 1) * LDT + ml] = va.y;
      As[(c4 * 4 + 2) * LDT + ml] = va.z;
      As[(c4 * 4 + 3) * LDT + ml] = va.w;
    }
    #pragma unroll
    for (int i = 0; i < 4; i++) {
      int f = i * 256 + tid;
      int kk = f >> 5, c4 = f & 31;
      float4 vb = *(const float4*)(Bw + (size_t)(k0 + kk) * N + n0 + c4 * 4);
      *(float4*)(Bs + kk * LDT + c4 * 4) = vb;
    }
    __syncthreads();
    #pragma unroll
    for (int kk = 0; kk < BKF; kk++) {
      const float4* ar = (const float4*)(As + kk * LDT);
      const float4* br = (const float4*)(Bs + kk * LDT);
      float4 a0 = ar[ty * 2], a1 = ar[ty * 2 + 1];
      float4 b0 = br[tx * 2], b1 = br[tx * 2 + 1];
      float av[8] = {a0.x, a0.y, a0.z, a0.w, a1.x, a1.y, a1.z, a1.w};
      float bvv[8] = {b0.x, b0.y, b0.z, b0.w, b1.x, b1.y, b1.z, b1.w};
      #pragma unroll
      for (int i = 0; i < 8; i++)
        #pragma unroll
        for (int j = 0; j < 8; j++)
          acc[i][j] = fmaf(av[i], bvv[j], acc[i][j]);
    }
    __syncthreads();
  }
  int mbase = m0 + ty * 8;
  int nbase = n0 + tx * 8;
  #pragma unroll
  for (int i = 0; i < 8; i++) {
    float* crow = C + (size_t)(mbase + i) * N + nbase;
    #pragma unroll
    for (int j = 0; j < 8; j++) crow[j] = acc[i][j] + bias[nbase + j];
  }
}

// ---------------- fused: MFMA flash attention + wt(fc_w) ----------------
// attn: QBLK=128, shared K/V fragments across q-row groups, ballot-gated
// defer-max (R17-proven tail win). blocks 512+: fc weight transpose.
__global__ __launch_bounds__(256) void k_attn_wt(
    const unsigned short* __restrict__ qb, const unsigned short* __restrict__ kb,
    const unsigned short* __restrict__ vtb, unsigned short* __restrict__ o,
    const float* __restrict__ fcw, unsigned short* __restrict__ fcwt) {
  __shared__ __align__(16) char lds[49152];  // K dbuf 16K | Vt dbuf 16K | P 4x4K
  int gid = blockIdx.x;
  int tid = threadIdx.x;

  if (gid >= 512) {
    int idx = gid - 512;
    wt_body(fcw, fcwt, VOCAB, (idx % 500) * 64, (idx / 500) * 64, tid,
            (float(*)[65])lds);
    return;
  }

  int qt = 15 - (gid >> 5);
  int bh = gid & 31;
  int b = bh >> 4, hh = bh & 15;
  int lane = tid & 63, wv = tid >> 6;
  int fr = lane & 15, fq = lane >> 4;
  int q0 = qt * 128;
  int qw0 = q0 + wv * 32;
  const char* Kg = (const char*)(kb + (size_t)bh * T * 64);
  const char* Vg = (const char*)(vtb + (size_t)bh * 64 * T);
  char* Pl = lds + 32768 + wv * 4096;

  s16x8 qf[2][2];
  #pragma unroll
  for (int g = 0; g < 2; g++) {
    const unsigned short* Qg = qb + ((size_t)bh * T + qw0 + g * 16) * 64;
    qf[g][0] = *(const s16x8*)(Qg + (size_t)fr * 64 + fq * 8);
    qf[g][1] = *(const s16x8*)(Qg + (size_t)fr * 64 + 32 + fq * 8);
  }

  f32x4 po[2][4];
  float mrow[2][4], lrow[2][4];
  #pragma unroll
  for (int g = 0; g < 2; g++)
    #pragma unroll
    for (int j = 0; j < 4; j++) {
      po[g][j] = (f32x4){0.f, 0.f, 0.f, 0.f};
      mrow[g][j] = -1e30f; lrow[g][j] = 0.f;
    }

  int ntiles = qt * 2 + 2;
  int i0 = tid, i1 = tid + 256;
  int sr0 = i0 >> 3, sc0 = ((i0 & 7) ^ (sr0 & 7)) << 4;
  int sr1 = i1 >> 3, sc1 = ((i1 & 7) ^ (sr1 & 7)) << 4;

  {
    gload16(Kg + (size_t)sr0 * 128 + sc0, lds + i0 * 16);
    gload16(Kg + (size_t)sr1 * 128 + sc1, lds + i1 * 16);
    gload16(Vg + (size_t)sr0 * (T * 2) + sc0, lds + 16384 + i0 * 16);
    gload16(Vg + (size_t)sr1 * (T * 2) + sc1, lds + 16384 + i1 * 16);
  }
  __syncthreads();
  int cur = 0;

  for (int kt = 0; kt < ntiles; kt++) {
    int kv0 = kt * 64;
    if (kt + 1 < ntiles) {
      size_t kvn = (size_t)(kv0 + 64);
      char* kd = lds + (cur ^ 1) * 8192;
      char* vd = lds + 16384 + (cur ^ 1) * 8192;
      gload16(Kg + (kvn + sr0) * 128 + sc0, kd + i0 * 16);
      gload16(Kg + (kvn + sr1) * 128 + sc1, kd + i1 * 16);
      gload16(Vg + (size_t)sr0 * (T * 2) + kvn * 2 + sc0, vd + i0 * 16);
      gload16(Vg + (size_t)sr1 * (T * 2) + kvn * 2 + sc1, vd + i1 * 16);
    }
    const char* Kt = lds + cur * 8192;
    const char* Vt = lds + 16384 + cur * 8192;

    f32x4 s[2][4];
    #pragma unroll
    for (int ni = 0; ni < 4; ni++) {
      int r = ni * 16 + fr;
      s16x8 kf0 = *(const s16x8*)(Kt + r * 128 + ((fq ^ (r & 7)) << 4));
      s16x8 kf1 = *(const s16x8*)(Kt + r * 128 + (((4 + fq) ^ (r & 7)) << 4));
      #pragma unroll
      for (int g = 0; g < 2; g++) {
        s[g][ni] = (f32x4){0.f, 0.f, 0.f, 0.f};
        s[g][ni] = __builtin_amdgcn_mfma_f32_16x16x32_bf16(qf[g][0], kf0, s[g][ni], 0, 0, 0);
        s[g][ni] = __builtin_amdgcn_mfma_f32_16x16x32_bf16(qf[g][1], kf1, s[g][ni], 0, 0, 0);
      }
    }

    #pragma unroll
    for (int g = 0; g < 2; g++) {
      int qw = qw0 + g * 16;
      bool needm = (kv0 + 63 > qw);
      #pragma unroll
      for (int jj = 0; jj < 4; jj++) {
        int row = qw + fq * 4 + jj;
        float tm = -1e30f;
        #pragma unroll
        for (int ni = 0; ni < 4; ni++) {
          float val = s[g][ni][jj] * 0.125f;
          if (needm) { int col = kv0 + ni * 16 + fr; if (col > row) val = -1e30f; }
          s[g][ni][jj] = val;
          tm = fmaxf(tm, val);
        }
        if (__any(tm > mrow[g][jj] + 8.f)) {
          float twm = tm;
          #pragma unroll
          for (int mk = 1; mk < 16; mk <<= 1) twm = fmaxf(twm, __shfl_xor(twm, mk));
          float nm = fmaxf(mrow[g][jj], twm);
          float corr = __expf(mrow[g][jj] - nm);
          mrow[g][jj] = nm;
          #pragma unroll
          for (int ni = 0; ni < 4; ni++) po[g][ni][jj] *= corr;
          lrow[g][jj] *= corr;
        }
        float mref = mrow[g][jj];
        float rs = 0.f;
        #pragma unroll
        for (int ni = 0; ni < 4; ni++) {
          float pv = __expf(s[g][ni][jj] - mref);
          s[g][ni][jj] = pv;
          rs += pv;
        }
        #pragma unroll
        for (int mk = 1; mk < 16; mk <<= 1) rs += __shfl_xor(rs, mk);
        lrow[g][jj] += rs;
      }
    }

    asm volatile("s_waitcnt lgkmcnt(0)" ::: "memory");
    #pragma unroll
    for (int g = 0; g < 2; g++) {
      char* Pg = Pl + g * 2048;
      #pragma unroll
      for (int ni = 0; ni < 4; ni++) {
        int col = ni * 16 + fr;
        #pragma unroll
        for (int jj = 0; jj < 4; jj++) {
          int qq = fq * 4 + jj;
          *(unsigned short*)(Pg + qq * 128 + (((col >> 3) ^ (qq & 7)) << 4) +
                             (col & 7) * 2) = f2bf(s[g][ni][jj]);
        }
      }
    }
    asm volatile("s_waitcnt lgkmcnt(0)" ::: "memory");

    s16x8 pa[2][2];
    #pragma unroll
    for (int g = 0; g < 2; g++) {
      const char* Pg = Pl + g * 2048;
      pa[g][0] = *(const s16x8*)(Pg + fr * 128 + ((fq ^ (fr & 7)) << 4));
      pa[g][1] = *(const s16x8*)(Pg + fr * 128 + (((4 + fq) ^ (fr & 7)) << 4));
    }
    #pragma unroll
    for (int ni = 0; ni < 4; ni++) {
      int r = ni * 16 + fr;
      s16x8 vf0 = *(const s16x8*)(Vt + r * 128 + ((fq ^ (r & 7)) << 4));
      s16x8 vf1 = *(const s16x8*)(Vt + r * 128 + (((4 + fq) ^ (r & 7)) << 4));
      #pragma unroll
      for (int g = 0; g < 2; g++) {
        po[g][ni] = __builtin_amdgcn_mfma_f32_16x16x32_bf16(pa[g][0], vf0, po[g][ni], 0, 0, 0);
        po[g][ni] = __builtin_amdgcn_mfma_f32_16x16x32_bf16(pa[g][1], vf1, po[g][ni], 0, 0, 0);
      }
    }
    __syncthreads();
    cur ^= 1;
  }

  #pragma unroll
  for (int g = 0; g < 2; g++)
    #pragma unroll
    for (int jj = 0; jj < 4; jj++) {
      float inv = 1.f / lrow[g][jj];
      int row = qw0 + g * 16 + fq * 4 + jj;
      unsigned short* orow = o + ((size_t)(b * T + row)) * E + hh * 64;
      #pragma unroll
      for (int ni = 0; ni < 4; ni++)
        orow[ni * 16 + fr] = f2bf(po[g][ni][jj] * inv);
    }
}

extern "C" void kernel_launch(void* const* d_in, const int* in_sizes, int n_in,
                              void* d_out, int out_size, void* d_ws, size_t ws_size,
                              hipStream_t stream) {
  const int*   x      = (const int*)d_in[0];
  const float* tok    = (const float*)d_in[1];
  const float* pos    = (const float*)d_in[2];
  const float* qkv_w  = (const float*)d_in[3];
  const float* qkv_b  = (const float*)d_in[4];
  const float* proj_w = (const float*)d_in[5];
  const float* proj_b = (const float*)d_in[6];
  const float* fc_w   = (const float*)d_in[7];
  const float* fc_b   = (const float*)d_in[8];
  float* out = (float*)d_out;
  float* ws  = (float*)d_ws;

  // scratch layout in d_out (fully overwritten by fc at the end)
  unsigned short* hb      = (unsigned short*)out;                     // 2,097,152 f
  unsigned short* qkv_wt  = (unsigned short*)(out + 2097152);         // 1,572,864 f
  unsigned short* qbuf    = (unsigned short*)(out + 3670016);         // 2,097,152 f
  unsigned short* kbuf    = (unsigned short*)(out + 5767168);         // 2,097,152 f
  unsigned short* vtbuf   = (unsigned short*)(out + 7864320);         // 2,097,152 f
  unsigned short* aob     = (unsigned short*)(out + 9961472);         // 2,097,152 f
  unsigned short* proj_wt = (unsigned short*)(out + 12058624);        //   524,288 f

  const size_t WS_FAST = (size_t)(2097152 + 16384000) * 4;

  k_pre<<<5120, 256, 0, stream>>>(x, tok, pos, hb, qkv_w, qkv_wt, proj_w, proj_wt);
  k_qkv<<<192, 512, 0, stream>>>(hb, qkv_wt, qkv_b, qbuf, kbuf, vtbuf);

  if (ws_size >= WS_FAST) {
    unsigned short* h2b   = (unsigned short*)ws;
    unsigned short* fc_wt = (unsigned short*)(ws + 2097152);
    k_attn_wt<<<8512, 256, 0, stream>>>(qbuf, kbuf, vtbuf, aob, fc_w, fc_wt);
    k_bgemm<2><<<dim3(E / 128, M / 128), 256, 0, stream>>>(
        aob, proj_wt, proj_b, nullptr, E, h2b);
    k_fc<<<dim3((M / 256) * (VOCAB / 256)), 512, 0, stream>>>(
        h2b, fc_wt, fc_b, out);
  } else {
    float* h2 = ws;
    k_attn_wt<<<512, 256, 0, stream>>>(qbuf, kbuf, vtbuf, aob, nullptr, nullptr);
    k_bgemm<0><<<dim3(E / 128, M / 128), 256, 0, stream>>>(
        aob, proj_wt, proj_b, h2, E, nullptr);
    k_gemm32<<<dim3(VOCAB / BN, M / BM), 256, 0, stream>>>(
        h2, fc_w, fc_b, out, VOCAB);
  }
}